// Round 3
// baseline (775.736 us; speedup 1.0000x reference)
//
#include <hip/hip_runtime.h>
#include <math.h>

#define NN 100000
#define NE 1600000
#define NB1 391          // ceil(NN/256) scan blocks
#define PART_BLOCKS 768  // k_gemm1 grid (3 blocks/CU)

// ws layout in 4-byte units
#define OFS_DEG   0
#define OFS_CUR   (NN)
#define OFS_RP    (2*NN)
#define OFS_BSUM  (3*NN)
#define OFS_BSCAN (3*NN + 512)
#define OFS_CSR   (3*NN + 1024)
#define OFS_INV   (3*NN + 1024 + NE)
#define OFS_HAS   (OFS_INV + NN)
#define OFS_H1    (OFS_HAS + NN)
#define OFS_AGG2  (OFS_H1 + 128*NN)
#define OFS_AGG1  (OFS_AGG2)            /* alias: agg1 consumed before agg2 written */
#define OFS_STATS (OFS_AGG2 + 128*NN)
#define OFS_PART  (OFS_STATS + 256)

// ---------------- CSR build ----------------
__global__ void k_hist(const int* __restrict__ ei, int* __restrict__ deg) {
    int e = blockIdx.x * 256 + threadIdx.x;
    if (e < NE) atomicAdd(&deg[ei[NE + e]], 1);
}

__global__ void k_scan1(const int* __restrict__ deg, int* __restrict__ bsum) {
    __shared__ int sb[256];
    int i = blockIdx.x * 256 + threadIdx.x;
    sb[threadIdx.x] = (i < NN) ? deg[i] : 0;
    __syncthreads();
    for (int off = 128; off > 0; off >>= 1) {
        if (threadIdx.x < off) sb[threadIdx.x] += sb[threadIdx.x + off];
        __syncthreads();
    }
    if (threadIdx.x == 0) bsum[blockIdx.x] = sb[0];
}

__global__ void k_scan2(const int* __restrict__ bsum, int* __restrict__ bscan) {
    __shared__ int sb[512];
    int t = threadIdx.x;
    int v = (t < NB1) ? bsum[t] : 0;
    sb[t] = v;
    __syncthreads();
    for (int off = 1; off < 512; off <<= 1) {
        int u = (t >= off) ? sb[t - off] : 0;
        __syncthreads();
        sb[t] += u;
        __syncthreads();
    }
    if (t < NB1) bscan[t] = sb[t] - v;   // exclusive
}

__global__ void k_scan3(const int* __restrict__ deg, const int* __restrict__ bscan,
                        int* __restrict__ rp, int* __restrict__ cur,
                        float* __restrict__ inv, float* __restrict__ has) {
    __shared__ int sb[256];
    int t = threadIdx.x;
    int i = blockIdx.x * 256 + t;
    int d = (i < NN) ? deg[i] : 0;
    sb[t] = d;
    __syncthreads();
    for (int off = 1; off < 256; off <<= 1) {
        int u = (t >= off) ? sb[t - off] : 0;
        __syncthreads();
        sb[t] += u;
        __syncthreads();
    }
    if (i < NN) {
        int start = sb[t] - d + bscan[blockIdx.x];  // exclusive prefix
        rp[i] = start;
        cur[i] = start;
        inv[i] = 1.0f / fmaxf((float)d, 1.0f);
        has[i] = (d > 0) ? 1.0f : 0.0f;
    }
}

__global__ void k_fill(const int* __restrict__ ei, int* __restrict__ cur,
                       int* __restrict__ csr) {
    int e = blockIdx.x * 256 + threadIdx.x;
    if (e < NE) {
        int d = ei[NE + e];
        int pos = atomicAdd(&cur[d], 1);
        csr[pos] = ei[e];
    }
}

// ---------------- gather-aggregate layer 1: agg1[n] = mean_{s in N(n)} x[s] ----------------
// 1 node/wave; 4 edge-slots x 16 float4-feature lanes
__global__ __launch_bounds__(256) void k_agg1(
    const float* __restrict__ x, const int* __restrict__ csr,
    const int* __restrict__ rp, const int* __restrict__ deg,
    const float* __restrict__ inv, float* __restrict__ agg1) {
    int t = threadIdx.x;
    int lane = t & 63;
    int eslot = lane >> 4, f4 = lane & 15;
    int node = blockIdx.x * 4 + (t >> 6);
    int len = deg[node];
    const int* cp = csr + rp[node];
    const float4* x4 = (const float4*)x;
    float4 a = {0.f, 0.f, 0.f, 0.f};
    for (int j = eslot; j < len; j += 4) {
        int s = cp[j];
        float4 v = x4[s * 16 + f4];
        a.x += v.x; a.y += v.y; a.z += v.z; a.w += v.w;
    }
    a.x += __shfl_xor(a.x, 16); a.y += __shfl_xor(a.y, 16);
    a.z += __shfl_xor(a.z, 16); a.w += __shfl_xor(a.w, 16);
    a.x += __shfl_xor(a.x, 32); a.y += __shfl_xor(a.y, 32);
    a.z += __shfl_xor(a.z, 32); a.w += __shfl_xor(a.w, 32);
    if (lane < 16) {
        float ic = inv[node];
        a.x *= ic; a.y *= ic; a.z *= ic; a.w *= ic;
        ((float4*)agg1)[node * 16 + f4] = a;
    }
}

// ---------------- gather-aggregate layer 2: agg2[n] = mean_{s in N(n)} h1[s] ----------------
// 1 node/wave; 2 edge-slots x 32 float4-feature lanes
__global__ __launch_bounds__(256) void k_agg2(
    const float* __restrict__ h1, const int* __restrict__ csr,
    const int* __restrict__ rp, const int* __restrict__ deg,
    const float* __restrict__ inv, float* __restrict__ agg2) {
    int t = threadIdx.x;
    int lane = t & 63;
    int eslot = lane >> 5, f4 = lane & 31;
    int node = blockIdx.x * 4 + (t >> 6);
    int len = deg[node];
    const int* cp = csr + rp[node];
    const float4* h4 = (const float4*)h1;
    float4 a = {0.f, 0.f, 0.f, 0.f};
    for (int j = eslot; j < len; j += 2) {
        int s = cp[j];
        float4 v = h4[s * 32 + f4];
        a.x += v.x; a.y += v.y; a.z += v.z; a.w += v.w;
    }
    a.x += __shfl_xor(a.x, 32); a.y += __shfl_xor(a.y, 32);
    a.z += __shfl_xor(a.z, 32); a.w += __shfl_xor(a.w, 32);
    if (lane < 32) {
        float ic = inv[node];
        a.x *= ic; a.y *= ic; a.z *= ic; a.w *= ic;
        ((float4*)agg2)[node * 32 + f4] = a;
    }
}

// ---------------- layer 1: out = agg1 @ w1l + b1l + x @ w1r ; L2norm ; relu ; BN col stats ----
// persistent grid-stride; 32-node tile; thread = 4 nodes x 4 cols (16 FMA per wt b128)
__global__ __launch_bounds__(256) void k_gemm1(
    const float* __restrict__ agg1, const float* __restrict__ x,
    const float* __restrict__ w1l, const float* __restrict__ b1l,
    const float* __restrict__ w1r,
    float* __restrict__ h1, float* __restrict__ part) {
    __shared__ float wt[64 * 128];   // 32 KB weight tile
    __shared__ float inA[32 * 64];   // 8 KB mean-agg rows
    __shared__ float inB[32 * 64];   // 8 KB x rows
    __shared__ float cs[128];
    __shared__ float cq[128];
    const int t = threadIdx.x;
    const int jq = t & 31;   // 4 cols: jq*4..jq*4+3
    const int ng = t >> 5;   // 4 nodes: ng*4..ng*4+3
    if (t < 128) { cs[t] = 0.f; cq[t] = 0.f; }
    float lsum[4] = {0, 0, 0, 0};
    float lsq[4]  = {0, 0, 0, 0};
    const float4* w1l4 = (const float4*)w1l;
    const float4* w1r4 = (const float4*)w1r;
    float4* wt4 = (float4*)wt;
    const float4 bv = ((const float4*)b1l)[jq];

    for (int g = blockIdx.x; g < NN / 32; g += gridDim.x) {
        const int base = g * 32;
        __syncthreads();  // previous tile's readers done
        {   // stage 32 nodes x 64 feats (2 float4 per thread per matrix)
#pragma unroll
            for (int i = 0; i < 2; i++) {
                int idx = t + 256 * i;
                int node = idx >> 4, kq = idx & 15;
                ((float4*)inA)[idx] = ((const float4*)agg1)[(base + node) * 16 + kq];
                ((float4*)inB)[idx] = ((const float4*)x)[(base + node) * 16 + kq];
            }
#pragma unroll
            for (int i = 0; i < 8; i++) wt4[t + 256 * i] = w1l4[t + 256 * i];
        }
        __syncthreads();

        float4 acc[4];
#pragma unroll
        for (int i = 0; i < 4; i++) acc[i] = bv;
        const int rb = (ng * 4) * 64;
#pragma unroll
        for (int k = 0; k < 64; k++) {
            float4 w4 = wt4[k * 32 + jq];
#pragma unroll
            for (int i = 0; i < 4; i++) {
                float a = inA[rb + i * 64 + k];
                acc[i].x += a * w4.x; acc[i].y += a * w4.y;
                acc[i].z += a * w4.z; acc[i].w += a * w4.w;
            }
        }
        __syncthreads();
#pragma unroll
        for (int i = 0; i < 8; i++) wt4[t + 256 * i] = w1r4[t + 256 * i];
        __syncthreads();
#pragma unroll
        for (int k = 0; k < 64; k++) {
            float4 w4 = wt4[k * 32 + jq];
#pragma unroll
            for (int i = 0; i < 4; i++) {
                float a = inB[rb + i * 64 + k];
                acc[i].x += a * w4.x; acc[i].y += a * w4.y;
                acc[i].z += a * w4.z; acc[i].w += a * w4.w;
            }
        }
        // epilogue: per node L2-normalize + relu + BN partial accum
#pragma unroll
        for (int i = 0; i < 4; i++) {
            float ss = acc[i].x * acc[i].x + acc[i].y * acc[i].y
                     + acc[i].z * acc[i].z + acc[i].w * acc[i].w;
            ss += __shfl_xor(ss, 1); ss += __shfl_xor(ss, 2); ss += __shfl_xor(ss, 4);
            ss += __shfl_xor(ss, 8); ss += __shfl_xor(ss, 16);
            float iv = 1.0f / fmaxf(sqrtf(ss), 1e-12f);
            float v0 = fmaxf(acc[i].x * iv, 0.f), v1 = fmaxf(acc[i].y * iv, 0.f);
            float v2 = fmaxf(acc[i].z * iv, 0.f), v3 = fmaxf(acc[i].w * iv, 0.f);
            float4 o; o.x = v0; o.y = v1; o.z = v2; o.w = v3;
            ((float4*)&h1[(base + ng * 4 + i) * 128])[jq] = o;
            lsum[0] += v0; lsum[1] += v1; lsum[2] += v2; lsum[3] += v3;
            lsq[0] += v0 * v0; lsq[1] += v1 * v1; lsq[2] += v2 * v2; lsq[3] += v3 * v3;
        }
    }
    // flush per-block BN partial stats
    __syncthreads();
#pragma unroll
    for (int c = 0; c < 4; c++) {
        atomicAdd(&cs[jq * 4 + c], lsum[c]);
        atomicAdd(&cq[jq * 4 + c], lsq[c]);
    }
    __syncthreads();
    if (t < 128) {
        part[blockIdx.x * 256 + t] = cs[t];
        part[blockIdx.x * 256 + 128 + t] = cq[t];
    }
}

// ---------------- BN finalize: scale/shift from partials ----------------
__global__ void k_bnfin(const float* __restrict__ part, const float* __restrict__ gamma,
                        const float* __restrict__ beta, float* __restrict__ stats) {
    int t = threadIdx.x;  // 128
    float s = 0.f, q = 0.f;
    for (int b = 0; b < PART_BLOCKS; b++) {
        s += part[b * 256 + t];
        q += part[b * 256 + 128 + t];
    }
    float mean = s / (float)NN;
    float var = q / (float)NN - mean * mean;
    float sc = gamma[t] * rsqrtf(var + 1e-5f);
    stats[t] = sc;
    stats[128 + t] = beta[t] - mean * sc;
}

// ---------------- layer 2 + L2norm + FC, fused (BN folded into staging) ----------------
// 32-node tile; thread = 4 nodes x 4 cols (16 FMA per wt b128); 64 KB LDS -> 2 blocks/CU
__global__ __launch_bounds__(256) void k_gemm2(
    const float* __restrict__ agg2, const float* __restrict__ h1,
    const float* __restrict__ has, const float* __restrict__ stats,
    const float* __restrict__ w2l, const float* __restrict__ b2l,
    const float* __restrict__ w2r,
    const float* __restrict__ wfc, const float* __restrict__ bfc,
    float* __restrict__ out) {
    __shared__ float wt[64 * 128];   // 32 KB K-chunk weight tile (reused for wfc)
    __shared__ float inA[32 * 128];  // 16 KB BN'd mean-agg rows; reused for normalized h2
    __shared__ float inB[32 * 128];  // 16 KB BN'd h1 rows
    const int t = threadIdx.x;
    const int jq = t & 31, ng = t >> 5;
    const int base = blockIdx.x * 32;
    float4* wt4 = (float4*)wt;
    const float4* stats4 = (const float4*)stats;

    // stage inputs: 32 nodes x 128 feats, 4 float4 per thread per matrix; BN applied here
#pragma unroll
    for (int i = 0; i < 4; i++) {
        int idx = t + 256 * i;
        int node = idx >> 5, kq = idx & 31;
        float4 sc = stats4[kq];
        float4 sh = stats4[32 + kq];
        float hv = has[base + node];
        float4 a = ((const float4*)agg2)[(base + node) * 32 + kq];
        a.x = a.x * sc.x + sh.x * hv; a.y = a.y * sc.y + sh.y * hv;
        a.z = a.z * sc.z + sh.z * hv; a.w = a.w * sc.w + sh.w * hv;
        ((float4*)inA)[idx] = a;
        float4 b = ((const float4*)h1)[(base + node) * 32 + kq];
        b.x = b.x * sc.x + sh.x; b.y = b.y * sc.y + sh.y;
        b.z = b.z * sc.z + sh.z; b.w = b.w * sc.w + sh.w;
        ((float4*)inB)[idx] = b;
    }
    const float4 bv = ((const float4*)b2l)[jq];
    float4 acc[4];
#pragma unroll
    for (int i = 0; i < 4; i++) acc[i] = bv;
    const int nb = ng * 4;

#pragma unroll
    for (int pass = 0; pass < 4; pass++) {
        const float4* W4 = (const float4*)((pass < 2) ? w2l : w2r);
        const int kc = pass & 1;
        __syncthreads();  // previous tile readers done (also covers staging on pass 0)
#pragma unroll
        for (int i = 0; i < 8; i++) wt4[t + 256 * i] = W4[kc * 2048 + t + 256 * i];
        __syncthreads();
        const float* IN = (pass < 2) ? inA : inB;
        const int rb = nb * 128 + kc * 64;
#pragma unroll
        for (int k = 0; k < 64; k++) {
            float4 w4 = wt4[k * 32 + jq];
#pragma unroll
            for (int i = 0; i < 4; i++) {
                float a = IN[rb + i * 128 + k];
                acc[i].x += a * w4.x; acc[i].y += a * w4.y;
                acc[i].z += a * w4.z; acc[i].w += a * w4.w;
            }
        }
    }
    __syncthreads();  // all wt/inA readers done (inA last read in pass 1, wt in pass 3)

    // normalize rows, write h2 into inA
#pragma unroll
    for (int i = 0; i < 4; i++) {
        float ss = acc[i].x * acc[i].x + acc[i].y * acc[i].y
                 + acc[i].z * acc[i].z + acc[i].w * acc[i].w;
        ss += __shfl_xor(ss, 1); ss += __shfl_xor(ss, 2); ss += __shfl_xor(ss, 4);
        ss += __shfl_xor(ss, 8); ss += __shfl_xor(ss, 16);
        float iv = 1.0f / fmaxf(sqrtf(ss), 1e-12f);
        float4 o; o.x = acc[i].x * iv; o.y = acc[i].y * iv;
        o.z = acc[i].z * iv; o.w = acc[i].w * iv;
        ((float4*)inA)[(nb + i) * 32 + jq] = o;
    }
    // load wfc (128x16 = 2048 floats) into wt
#pragma unroll
    for (int i = 0; i < 2; i++) wt4[t + 256 * i] = ((const float4*)wfc)[t + 256 * i];
    __syncthreads();
    // FC: 32 nodes x 16 outputs = 512 pairs, 2 per thread
#pragma unroll
    for (int i = 0; i < 2; i++) {
        int p = t + 256 * i;
        int n = p >> 4, o = p & 15;
        float s = bfc[o];
#pragma unroll
        for (int k = 0; k < 128; k++) s += inA[n * 128 + k] * wt[k * 16 + o];
        out[(base + n) * 16 + o] = s;
    }
}

extern "C" void kernel_launch(void* const* d_in, const int* in_sizes, int n_in,
                              void* d_out, int out_size, void* d_ws, size_t ws_size,
                              hipStream_t stream) {
    const float* x     = (const float*)d_in[0];
    const int*   ei    = (const int*)d_in[1];
    const float* w1l   = (const float*)d_in[2];
    const float* b1l   = (const float*)d_in[3];
    const float* w1r   = (const float*)d_in[4];
    const float* gamma = (const float*)d_in[5];
    const float* beta  = (const float*)d_in[6];
    const float* w2l   = (const float*)d_in[7];
    const float* b2l   = (const float*)d_in[8];
    const float* w2r   = (const float*)d_in[9];
    const float* wfc   = (const float*)d_in[10];
    const float* bfc   = (const float*)d_in[11];
    float* out = (float*)d_out;

    float* W = (float*)d_ws;
    int* deg   = (int*)(W + OFS_DEG);
    int* cur   = (int*)(W + OFS_CUR);
    int* rp    = (int*)(W + OFS_RP);
    int* bsum  = (int*)(W + OFS_BSUM);
    int* bscan = (int*)(W + OFS_BSCAN);
    int* csr   = (int*)(W + OFS_CSR);
    float* inv   = W + OFS_INV;
    float* has   = W + OFS_HAS;
    float* h1    = W + OFS_H1;
    float* agg1  = W + OFS_AGG1;
    float* agg2  = W + OFS_AGG2;
    float* stats = W + OFS_STATS;
    float* part  = W + OFS_PART;

    // zero degree histogram only
    hipMemsetAsync(deg, 0, NN * sizeof(int), stream);

    k_hist <<<(NE + 255) / 256, 256, 0, stream>>>(ei, deg);
    k_scan1<<<NB1, 256, 0, stream>>>(deg, bsum);
    k_scan2<<<1, 512, 0, stream>>>(bsum, bscan);
    k_scan3<<<NB1, 256, 0, stream>>>(deg, bscan, rp, cur, inv, has);
    k_fill <<<(NE + 255) / 256, 256, 0, stream>>>(ei, cur, csr);

    k_agg1 <<<NN / 4, 256, 0, stream>>>(x, csr, rp, deg, inv, agg1);
    k_gemm1<<<PART_BLOCKS, 256, 0, stream>>>(agg1, x, w1l, b1l, w1r, h1, part);
    k_bnfin<<<1, 128, 0, stream>>>(part, gamma, beta, stats);
    k_agg2 <<<NN / 4, 256, 0, stream>>>(h1, csr, rp, deg, inv, agg2);
    k_gemm2<<<NN / 32, 256, 0, stream>>>(agg2, h1, has, stats, w2l, b2l, w2r, wfc, bfc, out);
}

// Round 5
// 538.200 us; speedup vs baseline: 1.4414x; 1.4414x over previous
//
#include <hip/hip_runtime.h>
#include <math.h>

#define NN 100000
#define NE 1600000
#define NB1 391           // ceil(NN/256) scan blocks
#define PART_BLOCKS 768
#define NT1 1563          // ceil(NN/64) M-tiles
#define LDA 136           // padded LDS row stride (ushorts): 272 B, 16B-aligned

typedef float f32x4 __attribute__((ext_vector_type(4)));
typedef short s16x8 __attribute__((ext_vector_type(8)));

// ---- ws layout (4-byte words) ----
#define OFS_DEG   0
#define OFS_CUR   (NN)
#define OFS_RP    (2*NN)
#define OFS_BSUM  (3*NN)
#define OFS_BSCAN (3*NN + 512)
#define OFS_CSR   (3*NN + 1024)
#define OFS_INV   (OFS_CSR + NE)
#define OFS_HAS   (OFS_INV + NN)
#define OFS_XB    (OFS_HAS + NN)        // x bf16 [NN][64]   -> 32*NN words
#define OFS_A1B   (OFS_XB + 32*NN)      // agg1 bf16 [NN][64]-> 32*NN
#define OFS_H1B   (OFS_A1B + 32*NN)     // h1 bf16 [NN][128] -> 64*NN
#define OFS_A2B   (OFS_H1B + 64*NN)     // BN'd agg2 bf16 [NN][128] -> 64*NN
#define OFS_W1T   (OFS_A2B + 64*NN)     // [128][128] ush -> 8192 words
#define OFS_W2T   (OFS_W1T + 8192)      // [128][256] ush -> 16384 words  (BUGFIX: was +4096)
#define OFS_WFCT  (OFS_W2T + 16384)     // [16][128] ush -> 1024 words
#define OFS_STATS (OFS_WFCT + 1024)     // 256
#define OFS_PART  (OFS_STATS + 256)     // 768*256

__device__ __forceinline__ unsigned short f2bf(float f) {
    unsigned u = __float_as_uint(f);
    return (unsigned short)((u + 0x7FFFu + ((u >> 16) & 1u)) >> 16);
}
__device__ __forceinline__ float bfl(unsigned u) { return __uint_as_float(u << 16); }
__device__ __forceinline__ float bfh(unsigned u) { return __uint_as_float(u & 0xFFFF0000u); }

// ---------------- cast x -> bf16 ----------------
__global__ void k_cast(const float4* __restrict__ x4, uint2* __restrict__ xb) {
    int i = blockIdx.x * 256 + threadIdx.x;  // i < NN*16
    float4 v = x4[i];
    uint2 o;
    o.x = (unsigned)f2bf(v.x) | ((unsigned)f2bf(v.y) << 16);
    o.y = (unsigned)f2bf(v.z) | ((unsigned)f2bf(v.w) << 16);
    xb[i] = o;
}

// ---------------- weight prep: transposed bf16 ----------------
__global__ void k_prep(const float* __restrict__ w1l, const float* __restrict__ w1r,
                       const float* __restrict__ w2l, const float* __restrict__ w2r,
                       const float* __restrict__ wfc,
                       unsigned short* __restrict__ W1T, unsigned short* __restrict__ W2T,
                       unsigned short* __restrict__ wfcT) {
    int b = blockIdx.x, t = threadIdx.x;  // 128 threads
    if (b < 128) {
        int n = b, k = t;
        float v = (k < 64) ? w1l[k * 128 + n] : w1r[(k - 64) * 128 + n];
        W1T[n * 128 + k] = f2bf(v);
    } else if (b < 256) {
        int n = b - 128;
        W2T[n * 256 + t] = f2bf(w2l[t * 128 + n]);
        W2T[n * 256 + 128 + t] = f2bf(w2r[t * 128 + n]);
    } else {
        int o = b - 256;
        wfcT[o * 128 + t] = f2bf(wfc[t * 16 + o]);
    }
}

// ---------------- CSR build ----------------
__global__ void k_hist(const int* __restrict__ ei, int* __restrict__ deg) {
    int e = blockIdx.x * 256 + threadIdx.x;
    if (e < NE) atomicAdd(&deg[ei[NE + e]], 1);
}

__global__ void k_scan1(const int* __restrict__ deg, int* __restrict__ bsum) {
    __shared__ int sb[256];
    int i = blockIdx.x * 256 + threadIdx.x;
    sb[threadIdx.x] = (i < NN) ? deg[i] : 0;
    __syncthreads();
    for (int off = 128; off > 0; off >>= 1) {
        if (threadIdx.x < off) sb[threadIdx.x] += sb[threadIdx.x + off];
        __syncthreads();
    }
    if (threadIdx.x == 0) bsum[blockIdx.x] = sb[0];
}

__global__ void k_scan2(const int* __restrict__ bsum, int* __restrict__ bscan) {
    __shared__ int sb[512];
    int t = threadIdx.x;
    int v = (t < NB1) ? bsum[t] : 0;
    sb[t] = v;
    __syncthreads();
    for (int off = 1; off < 512; off <<= 1) {
        int u = (t >= off) ? sb[t - off] : 0;
        __syncthreads();
        sb[t] += u;
        __syncthreads();
    }
    if (t < NB1) bscan[t] = sb[t] - v;   // exclusive
}

__global__ void k_scan3(const int* __restrict__ deg, const int* __restrict__ bscan,
                        int* __restrict__ rp, int* __restrict__ cur,
                        float* __restrict__ inv, float* __restrict__ has) {
    __shared__ int sb[256];
    int t = threadIdx.x;
    int i = blockIdx.x * 256 + t;
    int d = (i < NN) ? deg[i] : 0;
    sb[t] = d;
    __syncthreads();
    for (int off = 1; off < 256; off <<= 1) {
        int u = (t >= off) ? sb[t - off] : 0;
        __syncthreads();
        sb[t] += u;
        __syncthreads();
    }
    if (i < NN) {
        int start = sb[t] - d + bscan[blockIdx.x];
        rp[i] = start;
        cur[i] = start;
        inv[i] = 1.0f / fmaxf((float)d, 1.0f);
        has[i] = (d > 0) ? 1.0f : 0.0f;
    }
}

__global__ void k_fill(const int* __restrict__ ei, int* __restrict__ cur,
                       int* __restrict__ csr) {
    int e = blockIdx.x * 256 + threadIdx.x;
    if (e < NE) {
        int d = ei[NE + e];
        int pos = atomicAdd(&cur[d], 1);
        csr[pos] = ei[e];
    }
}

// ---------------- gather layer 1: agg1b[n] = bf16(mean x[s]) ----------------
// 1 node/wave; 4 edge-slots x 16 lanes x 8B
__global__ __launch_bounds__(256) void k_agg1(
    const uint2* __restrict__ xb, const int* __restrict__ csr,
    const int* __restrict__ rp, const int* __restrict__ deg,
    const float* __restrict__ inv, uint2* __restrict__ agg1b) {
    int t = threadIdx.x;
    int lane = t & 63;
    int eslot = lane >> 4, f8 = lane & 15;
    int node = blockIdx.x * 4 + (t >> 6);
    int len = deg[node];
    const int* cp = csr + rp[node];
    float a0 = 0.f, a1 = 0.f, a2 = 0.f, a3 = 0.f;
    for (int j = eslot; j < len; j += 4) {
        int s = cp[j];
        uint2 u = xb[s * 16 + f8];
        a0 += bfl(u.x); a1 += bfh(u.x); a2 += bfl(u.y); a3 += bfh(u.y);
    }
    a0 += __shfl_xor(a0, 16); a1 += __shfl_xor(a1, 16);
    a2 += __shfl_xor(a2, 16); a3 += __shfl_xor(a3, 16);
    a0 += __shfl_xor(a0, 32); a1 += __shfl_xor(a1, 32);
    a2 += __shfl_xor(a2, 32); a3 += __shfl_xor(a3, 32);
    if (lane < 16) {
        float ic = inv[node];
        uint2 o;
        o.x = (unsigned)f2bf(a0 * ic) | ((unsigned)f2bf(a1 * ic) << 16);
        o.y = (unsigned)f2bf(a2 * ic) | ((unsigned)f2bf(a3 * ic) << 16);
        agg1b[node * 16 + f8] = o;
    }
}

// ---------------- gather layer 2 + BN fold: a2b[n] = bf16(mean(h1b)*sc + sh*has) --------
// 1 node/wave; 2 edge-slots x 32 lanes x 8B
__global__ __launch_bounds__(256) void k_agg2(
    const uint2* __restrict__ h1b, const int* __restrict__ csr,
    const int* __restrict__ rp, const int* __restrict__ deg,
    const float* __restrict__ inv, const float* __restrict__ has,
    const float* __restrict__ stats, uint2* __restrict__ a2b) {
    int t = threadIdx.x;
    int lane = t & 63;
    int eslot = lane >> 5, f8 = lane & 31;
    int node = blockIdx.x * 4 + (t >> 6);
    int len = deg[node];
    const int* cp = csr + rp[node];
    float a0 = 0.f, a1 = 0.f, a2 = 0.f, a3 = 0.f;
    for (int j = eslot; j < len; j += 2) {
        int s = cp[j];
        uint2 u = h1b[s * 32 + f8];
        a0 += bfl(u.x); a1 += bfh(u.x); a2 += bfl(u.y); a3 += bfh(u.y);
    }
    a0 += __shfl_xor(a0, 32); a1 += __shfl_xor(a1, 32);
    a2 += __shfl_xor(a2, 32); a3 += __shfl_xor(a3, 32);
    if (lane < 32) {
        float ic = inv[node], hv = has[node];
        float4 sc = ((const float4*)stats)[f8];
        float4 sh = ((const float4*)(stats + 128))[f8];
        float v0 = a0 * ic * sc.x + sh.x * hv;
        float v1 = a1 * ic * sc.y + sh.y * hv;
        float v2 = a2 * ic * sc.z + sh.z * hv;
        float v3 = a3 * ic * sc.w + sh.w * hv;
        uint2 o;
        o.x = (unsigned)f2bf(v0) | ((unsigned)f2bf(v1) << 16);
        o.y = (unsigned)f2bf(v2) | ((unsigned)f2bf(v3) << 16);
        a2b[node * 32 + f8] = o;
    }
}

// ---------------- layer 1 MFMA: C=[agg1|x]@[w1l;w1r]+b1l; L2norm; relu; BN stats; h1b ----
__global__ __launch_bounds__(256, 3) void k_gemm1(
    const uint4* __restrict__ agg1b, const uint4* __restrict__ xb,
    const uint4* __restrict__ W1T, const float* __restrict__ b1l,
    uint4* __restrict__ h1b, float* __restrict__ part) {
    __shared__ unsigned short Wsm[128 * LDA];  // 34816 B
    __shared__ unsigned short Asm[64 * LDA];   // 17408 B
    __shared__ float cs[128], cq[128];
    const int t = threadIdx.x;
    const int w = t >> 6, lane = t & 63, quad = lane >> 4, l15 = lane & 15;
    if (t < 128) { cs[t] = 0.f; cq[t] = 0.f; }
    // stage W1T once (row=256B=16 uint4)
    {
        int r = t >> 1, h = t & 1;
#pragma unroll
        for (int i = 0; i < 8; i++) {
            uint4 v = W1T[r * 16 + h * 8 + i];
            *(uint4*)&Wsm[r * LDA + h * 64 + i * 8] = v;
        }
    }
    float bias[8];
#pragma unroll
    for (int nt = 0; nt < 8; nt++) bias[nt] = b1l[nt * 16 + l15];
    float colsum[8] = {0, 0, 0, 0, 0, 0, 0, 0};
    float colsq[8]  = {0, 0, 0, 0, 0, 0, 0, 0};

    for (int g = blockIdx.x; g < NT1; g += gridDim.x) {
        const int base = g * 64;
        const int valid = (NN - base < 64) ? (NN - base) : 64;
        __syncthreads();  // prev readback / W staging done
        {   // stage A: row m = [agg1b row m (128B) | xb row m (128B)]
            int m = t >> 2, p = t & 3;
            bool ok = m < valid;
            int gm = base + m;
            const uint4* src = (p < 2) ? agg1b : xb;
            int pc = p & 1;
#pragma unroll
            for (int i = 0; i < 4; i++) {
                uint4 v = ok ? src[gm * 8 + pc * 4 + i] : make_uint4(0, 0, 0, 0);
                *(uint4*)&Asm[m * LDA + p * 32 + i * 8] = v;
            }
        }
        __syncthreads();
        f32x4 acc[8];
#pragma unroll
        for (int nt = 0; nt < 8; nt++) acc[nt] = (f32x4){bias[nt], bias[nt], bias[nt], bias[nt]};
#pragma unroll
        for (int kc = 0; kc < 4; kc++) {
            s16x8 af = *(const s16x8*)&Asm[(16 * w + l15) * LDA + kc * 32 + quad * 8];
#pragma unroll
            for (int nt = 0; nt < 8; nt++) {
                s16x8 bf = *(const s16x8*)&Wsm[(nt * 16 + l15) * LDA + kc * 32 + quad * 8];
                acc[nt] = __builtin_amdgcn_mfma_f32_16x16x32_bf16(af, bf, acc[nt], 0, 0, 0);
            }
        }
        // epilogue: norm+relu+stats, write h1 bf16 into Asm (own rows)
        float ssr[4] = {0, 0, 0, 0};
#pragma unroll
        for (int nt = 0; nt < 8; nt++)
#pragma unroll
            for (int r = 0; r < 4; r++) ssr[r] += acc[nt][r] * acc[nt][r];
#pragma unroll
        for (int r = 0; r < 4; r++) {
            ssr[r] += __shfl_xor(ssr[r], 1); ssr[r] += __shfl_xor(ssr[r], 2);
            ssr[r] += __shfl_xor(ssr[r], 4); ssr[r] += __shfl_xor(ssr[r], 8);
        }
#pragma unroll
        for (int r = 0; r < 4; r++) {
            int mrow = 16 * w + quad * 4 + r;
            float iv = 1.0f / fmaxf(sqrtf(ssr[r]), 1e-12f);
            bool okr = mrow < valid;
#pragma unroll
            for (int nt = 0; nt < 8; nt++) {
                float v = fmaxf(acc[nt][r] * iv, 0.f);
                if (!okr) v = 0.f;
                colsum[nt] += v;
                colsq[nt] += v * v;
                Asm[mrow * LDA + nt * 16 + l15] = f2bf(v);
            }
        }
        __syncthreads();
        {   // coalesced h1b store (row=256B=16 uint4)
            int m = t >> 2, p = t & 3;
            if (m < valid) {
                int gm = base + m;
#pragma unroll
                for (int i = 0; i < 4; i++) {
                    uint4 v = *(const uint4*)&Asm[m * LDA + p * 32 + i * 8];
                    h1b[gm * 16 + p * 4 + i] = v;
                }
            }
        }
    }
    __syncthreads();
#pragma unroll
    for (int nt = 0; nt < 8; nt++) {
        atomicAdd(&cs[nt * 16 + l15], colsum[nt]);
        atomicAdd(&cq[nt * 16 + l15], colsq[nt]);
    }
    __syncthreads();
    if (t < 128) {
        part[blockIdx.x * 256 + t] = cs[t];
        part[blockIdx.x * 256 + 128 + t] = cq[t];
    }
}

// ---------------- BN finalize ----------------
__global__ void k_bnfin(const float* __restrict__ part, const float* __restrict__ gamma,
                        const float* __restrict__ beta, float* __restrict__ stats) {
    int t = threadIdx.x;  // 128
    float s = 0.f, q = 0.f;
    for (int b = 0; b < PART_BLOCKS; b++) {
        s += part[b * 256 + t];
        q += part[b * 256 + 128 + t];
    }
    float mean = s / (float)NN;
    float var = q / (float)NN - mean * mean;
    float sc = gamma[t] * rsqrtf(var + 1e-5f);
    stats[t] = sc;
    stats[128 + t] = beta[t] - mean * sc;
}

// ---------------- layer 2 MFMA (K=256) + L2norm + FC ----------------
__global__ __launch_bounds__(256, 3) void k_gemm2(
    const uint4* __restrict__ a2b, const uint4* __restrict__ h1b,
    const float* __restrict__ stats,
    const uint4* __restrict__ W2T, const float* __restrict__ b2l,
    const uint4* __restrict__ wfcT, const float* __restrict__ bfc,
    float* __restrict__ out) {
    __shared__ unsigned short Wsm[128 * LDA];
    __shared__ unsigned short Asm[64 * LDA];
    const int t = threadIdx.x;
    const int w = t >> 6, lane = t & 63, quad = lane >> 4, l15 = lane & 15;
    const int base = blockIdx.x * 64;
    const int valid = (NN - base < 64) ? (NN - base) : 64;

    f32x4 acc[8];
#pragma unroll
    for (int nt = 0; nt < 8; nt++) {
        float b = b2l[nt * 16 + l15];
        acc[nt] = (f32x4){b, b, b, b};
    }

#pragma unroll
    for (int phase = 0; phase < 2; phase++) {
        if (phase) __syncthreads();  // prev MFMA reads done
        {   // stage W half (W2T row = 512B = 32 uint4)
            int r = t >> 1, h = t & 1;
#pragma unroll
            for (int i = 0; i < 8; i++) {
                uint4 v = W2T[r * 32 + phase * 16 + h * 8 + i];
                *(uint4*)&Wsm[r * LDA + h * 64 + i * 8] = v;
            }
        }
        {   // stage A half
            int m = t >> 2, p = t & 3;
            bool ok = m < valid;
            int gm = base + m;
            if (phase == 0) {
#pragma unroll
                for (int i = 0; i < 4; i++) {
                    uint4 v = ok ? a2b[gm * 16 + p * 4 + i] : make_uint4(0, 0, 0, 0);
                    *(uint4*)&Asm[m * LDA + p * 32 + i * 8] = v;
                }
            } else {
                const float4* sc4 = (const float4*)stats;
                const float4* sh4 = (const float4*)(stats + 128);
#pragma unroll
                for (int i = 0; i < 4; i++) {
                    uint4 v = make_uint4(0, 0, 0, 0);
                    if (ok) {
                        v = h1b[gm * 16 + p * 4 + i];
                        int c4 = (p * 32 + i * 8) >> 2;
                        float4 s0 = sc4[c4], s1 = sc4[c4 + 1];
                        float4 t0 = sh4[c4], t1 = sh4[c4 + 1];
                        float e0 = bfl(v.x) * s0.x + t0.x, e1 = bfh(v.x) * s0.y + t0.y;
                        float e2 = bfl(v.y) * s0.z + t0.z, e3 = bfh(v.y) * s0.w + t0.w;
                        float e4 = bfl(v.z) * s1.x + t1.x, e5 = bfh(v.z) * s1.y + t1.y;
                        float e6 = bfl(v.w) * s1.z + t1.z, e7 = bfh(v.w) * s1.w + t1.w;
                        v.x = (unsigned)f2bf(e0) | ((unsigned)f2bf(e1) << 16);
                        v.y = (unsigned)f2bf(e2) | ((unsigned)f2bf(e3) << 16);
                        v.z = (unsigned)f2bf(e4) | ((unsigned)f2bf(e5) << 16);
                        v.w = (unsigned)f2bf(e6) | ((unsigned)f2bf(e7) << 16);
                    }
                    *(uint4*)&Asm[m * LDA + p * 32 + i * 8] = v;
                }
            }
        }
        __syncthreads();
#pragma unroll
        for (int kc = 0; kc < 4; kc++) {
            s16x8 af = *(const s16x8*)&Asm[(16 * w + l15) * LDA + kc * 32 + quad * 8];
#pragma unroll
            for (int nt = 0; nt < 8; nt++) {
                s16x8 bf = *(const s16x8*)&Wsm[(nt * 16 + l15) * LDA + kc * 32 + quad * 8];
                acc[nt] = __builtin_amdgcn_mfma_f32_16x16x32_bf16(af, bf, acc[nt], 0, 0, 0);
            }
        }
    }
    // epilogue: L2 norm (no relu), h2 -> Asm (own rows)
    float ssr[4] = {0, 0, 0, 0};
#pragma unroll
    for (int nt = 0; nt < 8; nt++)
#pragma unroll
        for (int r = 0; r < 4; r++) ssr[r] += acc[nt][r] * acc[nt][r];
#pragma unroll
    for (int r = 0; r < 4; r++) {
        ssr[r] += __shfl_xor(ssr[r], 1); ssr[r] += __shfl_xor(ssr[r], 2);
        ssr[r] += __shfl_xor(ssr[r], 4); ssr[r] += __shfl_xor(ssr[r], 8);
    }
#pragma unroll
    for (int r = 0; r < 4; r++) {
        int mrow = 16 * w + quad * 4 + r;
        float iv = 1.0f / fmaxf(sqrtf(ssr[r]), 1e-12f);
#pragma unroll
        for (int nt = 0; nt < 8; nt++) {
            Asm[mrow * LDA + nt * 16 + l15] = f2bf(acc[nt][r] * iv);
        }
    }
    __syncthreads();  // h2 writes + all W reads done
    // stage wfcT (16 rows x 256B = 16 uint4/row)
    if (t < 64) {
        int n = t >> 2, p = t & 3;
#pragma unroll
        for (int i = 0; i < 4; i++) {
            uint4 v = wfcT[n * 16 + p * 4 + i];
            *(uint4*)&Wsm[n * LDA + p * 32 + i * 8] = v;
        }
    }
    __syncthreads();
    // FC: 16x16 tile per wave, K=128
    f32x4 a2;
    {
        float b = bfc[l15];
        a2 = (f32x4){b, b, b, b};
    }
#pragma unroll
    for (int kc = 0; kc < 4; kc++) {
        s16x8 af = *(const s16x8*)&Asm[(16 * w + l15) * LDA + kc * 32 + quad * 8];
        s16x8 bf = *(const s16x8*)&Wsm[l15 * LDA + kc * 32 + quad * 8];
        a2 = __builtin_amdgcn_mfma_f32_16x16x32_bf16(af, bf, a2, 0, 0, 0);
    }
#pragma unroll
    for (int r = 0; r < 4; r++) {
        int mrow = 16 * w + quad * 4 + r;
        if (mrow < valid) out[(base + mrow) * 16 + l15] = a2[r];
    }
}

extern "C" void kernel_launch(void* const* d_in, const int* in_sizes, int n_in,
                              void* d_out, int out_size, void* d_ws, size_t ws_size,
                              hipStream_t stream) {
    const float* x     = (const float*)d_in[0];
    const int*   ei    = (const int*)d_in[1];
    const float* w1l   = (const float*)d_in[2];
    const float* b1l   = (const float*)d_in[3];
    const float* w1r   = (const float*)d_in[4];
    const float* gamma = (const float*)d_in[5];
    const float* beta  = (const float*)d_in[6];
    const float* w2l   = (const float*)d_in[7];
    const float* b2l   = (const float*)d_in[8];
    const float* w2r   = (const float*)d_in[9];
    const float* wfc   = (const float*)d_in[10];
    const float* bfc   = (const float*)d_in[11];
    float* out = (float*)d_out;

    float* W = (float*)d_ws;
    int* deg   = (int*)(W + OFS_DEG);
    int* cur   = (int*)(W + OFS_CUR);
    int* rp    = (int*)(W + OFS_RP);
    int* bsum  = (int*)(W + OFS_BSUM);
    int* bscan = (int*)(W + OFS_BSCAN);
    int* csr   = (int*)(W + OFS_CSR);
    float* inv   = W + OFS_INV;
    float* has   = W + OFS_HAS;
    unsigned* xb   = (unsigned*)(W + OFS_XB);
    unsigned* a1b  = (unsigned*)(W + OFS_A1B);
    unsigned* h1b  = (unsigned*)(W + OFS_H1B);
    unsigned* a2b  = (unsigned*)(W + OFS_A2B);
    unsigned short* W1T  = (unsigned short*)(W + OFS_W1T);
    unsigned short* W2T  = (unsigned short*)(W + OFS_W2T);
    unsigned short* wfcT = (unsigned short*)(W + OFS_WFCT);
    float* stats = W + OFS_STATS;
    float* part  = W + OFS_PART;

    hipMemsetAsync(deg, 0, NN * sizeof(int), stream);

    k_cast<<<NN * 16 / 256, 256, 0, stream>>>((const float4*)x, (uint2*)xb);
    k_prep<<<272, 128, 0, stream>>>(w1l, w1r, w2l, w2r, wfc, W1T, W2T, wfcT);
    k_hist <<<(NE + 255) / 256, 256, 0, stream>>>(ei, deg);
    k_scan1<<<NB1, 256, 0, stream>>>(deg, bsum);
    k_scan2<<<1, 512, 0, stream>>>(bsum, bscan);
    k_scan3<<<NB1, 256, 0, stream>>>(deg, bscan, rp, cur, inv, has);
    k_fill <<<(NE + 255) / 256, 256, 0, stream>>>(ei, cur, csr);

    k_agg1 <<<NN / 4, 256, 0, stream>>>((const uint2*)xb, csr, rp, deg, inv, (uint2*)a1b);
    k_gemm1<<<PART_BLOCKS, 256, 0, stream>>>((const uint4*)a1b, (const uint4*)xb,
                                             (const uint4*)W1T, b1l, (uint4*)h1b, part);
    k_bnfin<<<1, 128, 0, stream>>>(part, gamma, beta, stats);
    k_agg2 <<<NN / 4, 256, 0, stream>>>((const uint2*)h1b, csr, rp, deg, inv, has, stats,
                                        (uint2*)a2b);
    k_gemm2<<<NT1, 256, 0, stream>>>((const uint4*)a2b, (const uint4*)h1b, stats,
                                     (const uint4*)W2T, b2l, (const uint4*)wfcT, bfc, out);
}

// Round 6
// 436.557 us; speedup vs baseline: 1.7769x; 1.2328x over previous
//
#include <hip/hip_runtime.h>
#include <math.h>

#define NN 100000
#define NE 1600000
#define NB1 391           // ceil(NN/256) scan blocks
#define PART_BLOCKS 768
#define NT1 1563          // ceil(NN/64) M-tiles
#define LDA 136           // padded LDS row stride (ushorts): 272 B, 16B-aligned

typedef float f32x4 __attribute__((ext_vector_type(4)));
typedef short s16x8 __attribute__((ext_vector_type(8)));

// ---- ws layout (4-byte words) ----
#define OFS_DEG8  0                     // int[8][NN] sharded histogram -> base8 after scan3
#define OFS_DEG   (8*NN)                // int[NN]
#define OFS_RP    (9*NN)                // int[NN]
#define OFS_BSUM  (10*NN)
#define OFS_BSCAN (10*NN + 512)
#define OFS_RANK  (10*NN + 1024)        // ushort[NE] -> NE/2 words
#define OFS_CSR   (OFS_RANK + NE/2)
#define OFS_INV   (OFS_CSR + NE)
#define OFS_HAS   (OFS_INV + NN)
#define OFS_XB    (OFS_HAS + NN)        // x bf16 [NN][64]   -> 32*NN words
#define OFS_A1B   (OFS_XB + 32*NN)      // agg1 bf16 [NN][64]-> 32*NN
#define OFS_H1B   (OFS_A1B + 32*NN)     // h1 bf16 [NN][128] -> 64*NN
#define OFS_A2B   (OFS_H1B + 64*NN)     // BN'd agg2 bf16 [NN][128] -> 64*NN
#define OFS_W1T   (OFS_A2B + 64*NN)     // [128][128] ush -> 8192 words
#define OFS_W2T   (OFS_W1T + 8192)      // [128][256] ush -> 16384 words
#define OFS_WFCT  (OFS_W2T + 16384)     // [16][128] ush -> 1024 words
#define OFS_STATS (OFS_WFCT + 1024)     // 256
#define OFS_PART  (OFS_STATS + 256)     // 768*256

__device__ __forceinline__ unsigned short f2bf(float f) {
    unsigned u = __float_as_uint(f);
    return (unsigned short)((u + 0x7FFFu + ((u >> 16) & 1u)) >> 16);
}
__device__ __forceinline__ float bfl(unsigned u) { return __uint_as_float(u << 16); }
__device__ __forceinline__ float bfh(unsigned u) { return __uint_as_float(u & 0xFFFF0000u); }

// ---------------- cast x -> bf16 ----------------
__global__ void k_cast(const float4* __restrict__ x4, uint2* __restrict__ xb) {
    int i = blockIdx.x * 256 + threadIdx.x;  // i < NN*16
    float4 v = x4[i];
    uint2 o;
    o.x = (unsigned)f2bf(v.x) | ((unsigned)f2bf(v.y) << 16);
    o.y = (unsigned)f2bf(v.z) | ((unsigned)f2bf(v.w) << 16);
    xb[i] = o;
}

// ---------------- weight prep: transposed bf16 ----------------
__global__ void k_prep(const float* __restrict__ w1l, const float* __restrict__ w1r,
                       const float* __restrict__ w2l, const float* __restrict__ w2r,
                       const float* __restrict__ wfc,
                       unsigned short* __restrict__ W1T, unsigned short* __restrict__ W2T,
                       unsigned short* __restrict__ wfcT) {
    int b = blockIdx.x, t = threadIdx.x;  // 128 threads
    if (b < 128) {
        int n = b, k = t;
        float v = (k < 64) ? w1l[k * 128 + n] : w1r[(k - 64) * 128 + n];
        W1T[n * 128 + k] = f2bf(v);
    } else if (b < 256) {
        int n = b - 128;
        W2T[n * 256 + t] = f2bf(w2l[t * 128 + n]);
        W2T[n * 256 + 128 + t] = f2bf(w2r[t * 128 + n]);
    } else {
        int o = b - 256;
        wfcT[o * 128 + t] = f2bf(wfc[t * 16 + o]);
    }
}

// ---------------- CSR build: sharded rank histogram ----------------
// copy c = blockIdx&7 (~XCD-local); one atomic per edge total (k_hist is gone)
__global__ void k_rank(const int* __restrict__ ei, int* __restrict__ deg8,
                       unsigned short* __restrict__ rank) {
    int e = blockIdx.x * 256 + threadIdx.x;
    int c = blockIdx.x & 7;
    int d = ei[NE + e];
    int r = atomicAdd(&deg8[c * NN + d], 1);
    rank[e] = (unsigned short)r;
}

// sum 8 copies -> deg, per-block sums for scan
__global__ void k_scan1(const int* __restrict__ deg8, int* __restrict__ deg,
                        int* __restrict__ bsum) {
    __shared__ int sb[256];
    int t = threadIdx.x;
    int i = blockIdx.x * 256 + t;
    int s = 0;
    if (i < NN) {
#pragma unroll
        for (int c = 0; c < 8; c++) s += deg8[c * NN + i];
        deg[i] = s;
    }
    sb[t] = s;
    __syncthreads();
    for (int off = 128; off > 0; off >>= 1) {
        if (t < off) sb[t] += sb[t + off];
        __syncthreads();
    }
    if (t == 0) bsum[blockIdx.x] = sb[0];
}

__global__ void k_scan2(const int* __restrict__ bsum, int* __restrict__ bscan) {
    __shared__ int sb[512];
    int t = threadIdx.x;
    int v = (t < NB1) ? bsum[t] : 0;
    sb[t] = v;
    __syncthreads();
    for (int off = 1; off < 512; off <<= 1) {
        int u = (t >= off) ? sb[t - off] : 0;
        __syncthreads();
        sb[t] += u;
        __syncthreads();
    }
    if (t < NB1) bscan[t] = sb[t] - v;   // exclusive
}

// per-node start offsets; deg8 converted in place to base8[c][n] = rp[n] + pfx_c[n]
__global__ void k_scan3(const int* __restrict__ deg, const int* __restrict__ bscan,
                        int* __restrict__ rp, int* __restrict__ base8,
                        float* __restrict__ inv, float* __restrict__ has) {
    __shared__ int sb[256];
    int t = threadIdx.x;
    int i = blockIdx.x * 256 + t;
    int d = (i < NN) ? deg[i] : 0;
    sb[t] = d;
    __syncthreads();
    for (int off = 1; off < 256; off <<= 1) {
        int u = (t >= off) ? sb[t - off] : 0;
        __syncthreads();
        sb[t] += u;
        __syncthreads();
    }
    if (i < NN) {
        int start = sb[t] - d + bscan[blockIdx.x];
        rp[i] = start;
        inv[i] = 1.0f / fmaxf((float)d, 1.0f);
        has[i] = (d > 0) ? 1.0f : 0.0f;
        int run = start;
#pragma unroll
        for (int c = 0; c < 8; c++) {
            int dc = base8[c * NN + i];
            base8[c * NN + i] = run;
            run += dc;
        }
    }
}

// atomic-free fill; NT store to reduce cross-XCD L2 line ping-pong
__global__ void k_fill(const int* __restrict__ ei, const unsigned short* __restrict__ rank,
                       const int* __restrict__ base8, int* __restrict__ csr) {
    int e = blockIdx.x * 256 + threadIdx.x;
    int c = blockIdx.x & 7;
    int d = ei[NE + e];
    int s = ei[e];
    int pos = base8[c * NN + d] + (int)rank[e];
    __builtin_nontemporal_store(s, &csr[pos]);
}

// ---------------- gather layer 1: agg1b[n] = bf16(mean x[s]) ----------------
// 1 node/wave; 8 edge-chains x 8 lanes x 16B
__global__ __launch_bounds__(256) void k_agg1(
    const uint4* __restrict__ xb, const int* __restrict__ csr,
    const int* __restrict__ rp, const int* __restrict__ deg,
    const float* __restrict__ inv, uint4* __restrict__ agg1b) {
    int t = threadIdx.x;
    int lane = t & 63;
    int eslot = lane >> 3, f16 = lane & 7;
    int node = blockIdx.x * 4 + (t >> 6);
    int len = deg[node];
    const int* cp = csr + rp[node];
    float a[8] = {0, 0, 0, 0, 0, 0, 0, 0};
    for (int j = eslot; j < len; j += 8) {
        int s = cp[j];
        uint4 u = xb[s * 8 + f16];
        a[0] += bfl(u.x); a[1] += bfh(u.x); a[2] += bfl(u.y); a[3] += bfh(u.y);
        a[4] += bfl(u.z); a[5] += bfh(u.z); a[6] += bfl(u.w); a[7] += bfh(u.w);
    }
#pragma unroll
    for (int k = 0; k < 8; k++) {
        a[k] += __shfl_xor(a[k], 8);
        a[k] += __shfl_xor(a[k], 16);
        a[k] += __shfl_xor(a[k], 32);
    }
    if (lane < 8) {
        float ic = inv[node];
        uint4 o;
        o.x = (unsigned)f2bf(a[0] * ic) | ((unsigned)f2bf(a[1] * ic) << 16);
        o.y = (unsigned)f2bf(a[2] * ic) | ((unsigned)f2bf(a[3] * ic) << 16);
        o.z = (unsigned)f2bf(a[4] * ic) | ((unsigned)f2bf(a[5] * ic) << 16);
        o.w = (unsigned)f2bf(a[6] * ic) | ((unsigned)f2bf(a[7] * ic) << 16);
        agg1b[node * 8 + f16] = o;
    }
}

// ---------------- gather layer 2 + BN fold ----------------
// 1 node/wave; 4 edge-chains x 16 lanes x 16B
__global__ __launch_bounds__(256) void k_agg2(
    const uint4* __restrict__ h1b, const int* __restrict__ csr,
    const int* __restrict__ rp, const int* __restrict__ deg,
    const float* __restrict__ inv, const float* __restrict__ has,
    const float* __restrict__ stats, uint4* __restrict__ a2b) {
    int t = threadIdx.x;
    int lane = t & 63;
    int eslot = lane >> 4, f16 = lane & 15;
    int node = blockIdx.x * 4 + (t >> 6);
    int len = deg[node];
    const int* cp = csr + rp[node];
    float a[8] = {0, 0, 0, 0, 0, 0, 0, 0};
    for (int j = eslot; j < len; j += 4) {
        int s = cp[j];
        uint4 u = h1b[s * 16 + f16];
        a[0] += bfl(u.x); a[1] += bfh(u.x); a[2] += bfl(u.y); a[3] += bfh(u.y);
        a[4] += bfl(u.z); a[5] += bfh(u.z); a[6] += bfl(u.w); a[7] += bfh(u.w);
    }
#pragma unroll
    for (int k = 0; k < 8; k++) {
        a[k] += __shfl_xor(a[k], 16);
        a[k] += __shfl_xor(a[k], 32);
    }
    if (lane < 16) {
        float ic = inv[node], hv = has[node];
        float4 s0 = ((const float4*)stats)[f16 * 2];
        float4 s1 = ((const float4*)stats)[f16 * 2 + 1];
        float4 t0 = ((const float4*)(stats + 128))[f16 * 2];
        float4 t1 = ((const float4*)(stats + 128))[f16 * 2 + 1];
        float v0 = a[0] * ic * s0.x + t0.x * hv;
        float v1 = a[1] * ic * s0.y + t0.y * hv;
        float v2 = a[2] * ic * s0.z + t0.z * hv;
        float v3 = a[3] * ic * s0.w + t0.w * hv;
        float v4 = a[4] * ic * s1.x + t1.x * hv;
        float v5 = a[5] * ic * s1.y + t1.y * hv;
        float v6 = a[6] * ic * s1.z + t1.z * hv;
        float v7 = a[7] * ic * s1.w + t1.w * hv;
        uint4 o;
        o.x = (unsigned)f2bf(v0) | ((unsigned)f2bf(v1) << 16);
        o.y = (unsigned)f2bf(v2) | ((unsigned)f2bf(v3) << 16);
        o.z = (unsigned)f2bf(v4) | ((unsigned)f2bf(v5) << 16);
        o.w = (unsigned)f2bf(v6) | ((unsigned)f2bf(v7) << 16);
        a2b[node * 16 + f16] = o;
    }
}

// ---------------- layer 1 MFMA: C=[agg1|x]@[w1l;w1r]+b1l; L2norm; relu; BN stats; h1b ----
__global__ __launch_bounds__(256, 3) void k_gemm1(
    const uint4* __restrict__ agg1b, const uint4* __restrict__ xb,
    const uint4* __restrict__ W1T, const float* __restrict__ b1l,
    uint4* __restrict__ h1b, float* __restrict__ part) {
    __shared__ unsigned short Wsm[128 * LDA];  // 34816 B
    __shared__ unsigned short Asm[64 * LDA];   // 17408 B
    __shared__ float cs[128], cq[128];
    const int t = threadIdx.x;
    const int w = t >> 6, lane = t & 63, quad = lane >> 4, l15 = lane & 15;
    if (t < 128) { cs[t] = 0.f; cq[t] = 0.f; }
    // stage W1T once (row=256B=16 uint4)
    {
        int r = t >> 1, h = t & 1;
#pragma unroll
        for (int i = 0; i < 8; i++) {
            uint4 v = W1T[r * 16 + h * 8 + i];
            *(uint4*)&Wsm[r * LDA + h * 64 + i * 8] = v;
        }
    }
    float bias[8];
#pragma unroll
    for (int nt = 0; nt < 8; nt++) bias[nt] = b1l[nt * 16 + l15];
    float colsum[8] = {0, 0, 0, 0, 0, 0, 0, 0};
    float colsq[8]  = {0, 0, 0, 0, 0, 0, 0, 0};

    for (int g = blockIdx.x; g < NT1; g += gridDim.x) {
        const int base = g * 64;
        const int valid = (NN - base < 64) ? (NN - base) : 64;
        __syncthreads();  // prev readback / W staging done
        {   // stage A: row m = [agg1b row m (128B) | xb row m (128B)]
            int m = t >> 2, p = t & 3;
            bool ok = m < valid;
            int gm = base + m;
            const uint4* src = (p < 2) ? agg1b : xb;
            int pc = p & 1;
#pragma unroll
            for (int i = 0; i < 4; i++) {
                uint4 v = ok ? src[gm * 8 + pc * 4 + i] : make_uint4(0, 0, 0, 0);
                *(uint4*)&Asm[m * LDA + p * 32 + i * 8] = v;
            }
        }
        __syncthreads();
        f32x4 acc[8];
#pragma unroll
        for (int nt = 0; nt < 8; nt++) acc[nt] = (f32x4){bias[nt], bias[nt], bias[nt], bias[nt]};
#pragma unroll
        for (int kc = 0; kc < 4; kc++) {
            s16x8 af = *(const s16x8*)&Asm[(16 * w + l15) * LDA + kc * 32 + quad * 8];
#pragma unroll
            for (int nt = 0; nt < 8; nt++) {
                s16x8 bf = *(const s16x8*)&Wsm[(nt * 16 + l15) * LDA + kc * 32 + quad * 8];
                acc[nt] = __builtin_amdgcn_mfma_f32_16x16x32_bf16(af, bf, acc[nt], 0, 0, 0);
            }
        }
        // epilogue: norm+relu+stats, write h1 bf16 into Asm (own rows)
        float ssr[4] = {0, 0, 0, 0};
#pragma unroll
        for (int nt = 0; nt < 8; nt++)
#pragma unroll
            for (int r = 0; r < 4; r++) ssr[r] += acc[nt][r] * acc[nt][r];
#pragma unroll
        for (int r = 0; r < 4; r++) {
            ssr[r] += __shfl_xor(ssr[r], 1); ssr[r] += __shfl_xor(ssr[r], 2);
            ssr[r] += __shfl_xor(ssr[r], 4); ssr[r] += __shfl_xor(ssr[r], 8);
        }
#pragma unroll
        for (int r = 0; r < 4; r++) {
            int mrow = 16 * w + quad * 4 + r;
            float iv = 1.0f / fmaxf(sqrtf(ssr[r]), 1e-12f);
            bool okr = mrow < valid;
#pragma unroll
            for (int nt = 0; nt < 8; nt++) {
                float v = fmaxf(acc[nt][r] * iv, 0.f);
                if (!okr) v = 0.f;
                colsum[nt] += v;
                colsq[nt] += v * v;
                Asm[mrow * LDA + nt * 16 + l15] = f2bf(v);
            }
        }
        __syncthreads();
        {   // coalesced h1b store (row=256B=16 uint4)
            int m = t >> 2, p = t & 3;
            if (m < valid) {
                int gm = base + m;
#pragma unroll
                for (int i = 0; i < 4; i++) {
                    uint4 v = *(const uint4*)&Asm[m * LDA + p * 32 + i * 8];
                    h1b[gm * 16 + p * 4 + i] = v;
                }
            }
        }
    }
    __syncthreads();
#pragma unroll
    for (int nt = 0; nt < 8; nt++) {
        atomicAdd(&cs[nt * 16 + l15], colsum[nt]);
        atomicAdd(&cq[nt * 16 + l15], colsq[nt]);
    }
    __syncthreads();
    if (t < 128) {
        part[blockIdx.x * 256 + t] = cs[t];
        part[blockIdx.x * 256 + 128 + t] = cq[t];
    }
}

// ---------------- BN finalize ----------------
__global__ void k_bnfin(const float* __restrict__ part, const float* __restrict__ gamma,
                        const float* __restrict__ beta, float* __restrict__ stats) {
    int t = threadIdx.x;  // 128
    float s = 0.f, q = 0.f;
    for (int b = 0; b < PART_BLOCKS; b++) {
        s += part[b * 256 + t];
        q += part[b * 256 + 128 + t];
    }
    float mean = s / (float)NN;
    float var = q / (float)NN - mean * mean;
    float sc = gamma[t] * rsqrtf(var + 1e-5f);
    stats[t] = sc;
    stats[128 + t] = beta[t] - mean * sc;
}

// ---------------- layer 2 MFMA (K=256) + L2norm + FC ----------------
__global__ __launch_bounds__(256, 3) void k_gemm2(
    const uint4* __restrict__ a2b, const uint4* __restrict__ h1b,
    const float* __restrict__ stats,
    const uint4* __restrict__ W2T, const float* __restrict__ b2l,
    const uint4* __restrict__ wfcT, const float* __restrict__ bfc,
    float* __restrict__ out) {
    __shared__ unsigned short Wsm[128 * LDA];
    __shared__ unsigned short Asm[64 * LDA];
    const int t = threadIdx.x;
    const int w = t >> 6, lane = t & 63, quad = lane >> 4, l15 = lane & 15;
    const int base = blockIdx.x * 64;
    const int valid = (NN - base < 64) ? (NN - base) : 64;

    f32x4 acc[8];
#pragma unroll
    for (int nt = 0; nt < 8; nt++) {
        float b = b2l[nt * 16 + l15];
        acc[nt] = (f32x4){b, b, b, b};
    }

#pragma unroll
    for (int phase = 0; phase < 2; phase++) {
        if (phase) __syncthreads();  // prev MFMA reads done
        {   // stage W half (W2T row = 512B = 32 uint4)
            int r = t >> 1, h = t & 1;
#pragma unroll
            for (int i = 0; i < 8; i++) {
                uint4 v = W2T[r * 32 + phase * 16 + h * 8 + i];
                *(uint4*)&Wsm[r * LDA + h * 64 + i * 8] = v;
            }
        }
        {   // stage A half
            int m = t >> 2, p = t & 3;
            bool ok = m < valid;
            int gm = base + m;
            if (phase == 0) {
#pragma unroll
                for (int i = 0; i < 4; i++) {
                    uint4 v = ok ? a2b[gm * 16 + p * 4 + i] : make_uint4(0, 0, 0, 0);
                    *(uint4*)&Asm[m * LDA + p * 32 + i * 8] = v;
                }
            } else {
                const float4* sc4 = (const float4*)stats;
                const float4* sh4 = (const float4*)(stats + 128);
#pragma unroll
                for (int i = 0; i < 4; i++) {
                    uint4 v = make_uint4(0, 0, 0, 0);
                    if (ok) {
                        v = h1b[gm * 16 + p * 4 + i];
                        int c4 = (p * 32 + i * 8) >> 2;
                        float4 s0 = sc4[c4], s1 = sc4[c4 + 1];
                        float4 t0 = sh4[c4], t1 = sh4[c4 + 1];
                        float e0 = bfl(v.x) * s0.x + t0.x, e1 = bfh(v.x) * s0.y + t0.y;
                        float e2 = bfl(v.y) * s0.z + t0.z, e3 = bfh(v.y) * s0.w + t0.w;
                        float e4 = bfl(v.z) * s1.x + t1.x, e5 = bfh(v.z) * s1.y + t1.y;
                        float e6 = bfl(v.w) * s1.z + t1.z, e7 = bfh(v.w) * s1.w + t1.w;
                        v.x = (unsigned)f2bf(e0) | ((unsigned)f2bf(e1) << 16);
                        v.y = (unsigned)f2bf(e2) | ((unsigned)f2bf(e3) << 16);
                        v.z = (unsigned)f2bf(e4) | ((unsigned)f2bf(e5) << 16);
                        v.w = (unsigned)f2bf(e6) | ((unsigned)f2bf(e7) << 16);
                    }
                    *(uint4*)&Asm[m * LDA + p * 32 + i * 8] = v;
                }
            }
        }
        __syncthreads();
#pragma unroll
        for (int kc = 0; kc < 4; kc++) {
            s16x8 af = *(const s16x8*)&Asm[(16 * w + l15) * LDA + kc * 32 + quad * 8];
#pragma unroll
            for (int nt = 0; nt < 8; nt++) {
                s16x8 bf = *(const s16x8*)&Wsm[(nt * 16 + l15) * LDA + kc * 32 + quad * 8];
                acc[nt] = __builtin_amdgcn_mfma_f32_16x16x32_bf16(af, bf, acc[nt], 0, 0, 0);
            }
        }
    }
    // epilogue: L2 norm (no relu), h2 -> Asm (own rows)
    float ssr[4] = {0, 0, 0, 0};
#pragma unroll
    for (int nt = 0; nt < 8; nt++)
#pragma unroll
        for (int r = 0; r < 4; r++) ssr[r] += acc[nt][r] * acc[nt][r];
#pragma unroll
    for (int r = 0; r < 4; r++) {
        ssr[r] += __shfl_xor(ssr[r], 1); ssr[r] += __shfl_xor(ssr[r], 2);
        ssr[r] += __shfl_xor(ssr[r], 4); ssr[r] += __shfl_xor(ssr[r], 8);
    }
#pragma unroll
    for (int r = 0; r < 4; r++) {
        int mrow = 16 * w + quad * 4 + r;
        float iv = 1.0f / fmaxf(sqrtf(ssr[r]), 1e-12f);
#pragma unroll
        for (int nt = 0; nt < 8; nt++) {
            Asm[mrow * LDA + nt * 16 + l15] = f2bf(acc[nt][r] * iv);
        }
    }
    __syncthreads();  // h2 writes + all W reads done
    // stage wfcT (16 rows x 256B = 16 uint4/row)
    if (t < 64) {
        int n = t >> 2, p = t & 3;
#pragma unroll
        for (int i = 0; i < 4; i++) {
            uint4 v = wfcT[n * 16 + p * 4 + i];
            *(uint4*)&Wsm[n * LDA + p * 32 + i * 8] = v;
        }
    }
    __syncthreads();
    // FC: 16x16 tile per wave, K=128
    f32x4 a2;
    {
        float b = bfc[l15];
        a2 = (f32x4){b, b, b, b};
    }
#pragma unroll
    for (int kc = 0; kc < 4; kc++) {
        s16x8 af = *(const s16x8*)&Asm[(16 * w + l15) * LDA + kc * 32 + quad * 8];
        s16x8 bf = *(const s16x8*)&Wsm[l15 * LDA + kc * 32 + quad * 8];
        a2 = __builtin_amdgcn_mfma_f32_16x16x32_bf16(af, bf, a2, 0, 0, 0);
    }
#pragma unroll
    for (int r = 0; r < 4; r++) {
        int mrow = 16 * w + quad * 4 + r;
        if (mrow < valid) out[(base + mrow) * 16 + l15] = a2[r];
    }
}

extern "C" void kernel_launch(void* const* d_in, const int* in_sizes, int n_in,
                              void* d_out, int out_size, void* d_ws, size_t ws_size,
                              hipStream_t stream) {
    const float* x     = (const float*)d_in[0];
    const int*   ei    = (const int*)d_in[1];
    const float* w1l   = (const float*)d_in[2];
    const float* b1l   = (const float*)d_in[3];
    const float* w1r   = (const float*)d_in[4];
    const float* gamma = (const float*)d_in[5];
    const float* beta  = (const float*)d_in[6];
    const float* w2l   = (const float*)d_in[7];
    const float* b2l   = (const float*)d_in[8];
    const float* w2r   = (const float*)d_in[9];
    const float* wfc   = (const float*)d_in[10];
    const float* bfc   = (const float*)d_in[11];
    float* out = (float*)d_out;

    float* W = (float*)d_ws;
    int* deg8  = (int*)(W + OFS_DEG8);
    int* deg   = (int*)(W + OFS_DEG);
    int* rp    = (int*)(W + OFS_RP);
    int* bsum  = (int*)(W + OFS_BSUM);
    int* bscan = (int*)(W + OFS_BSCAN);
    unsigned short* rank = (unsigned short*)(W + OFS_RANK);
    int* csr   = (int*)(W + OFS_CSR);
    float* inv   = W + OFS_INV;
    float* has   = W + OFS_HAS;
    unsigned* xb   = (unsigned*)(W + OFS_XB);
    unsigned* a1b  = (unsigned*)(W + OFS_A1B);
    unsigned* h1b  = (unsigned*)(W + OFS_H1B);
    unsigned* a2b  = (unsigned*)(W + OFS_A2B);
    unsigned short* W1T  = (unsigned short*)(W + OFS_W1T);
    unsigned short* W2T  = (unsigned short*)(W + OFS_W2T);
    unsigned short* wfcT = (unsigned short*)(W + OFS_WFCT);
    float* stats = W + OFS_STATS;
    float* part  = W + OFS_PART;

    hipMemsetAsync(deg8, 0, 8 * NN * sizeof(int), stream);

    k_cast<<<NN * 16 / 256, 256, 0, stream>>>((const float4*)x, (uint2*)xb);
    k_prep<<<272, 128, 0, stream>>>(w1l, w1r, w2l, w2r, wfc, W1T, W2T, wfcT);
    k_rank <<<NE / 256, 256, 0, stream>>>(ei, deg8, rank);
    k_scan1<<<NB1, 256, 0, stream>>>(deg8, deg, bsum);
    k_scan2<<<1, 512, 0, stream>>>(bsum, bscan);
    k_scan3<<<NB1, 256, 0, stream>>>(deg, bscan, rp, deg8, inv, has);
    k_fill <<<NE / 256, 256, 0, stream>>>(ei, rank, deg8, csr);

    k_agg1 <<<NN / 4, 256, 0, stream>>>((const uint4*)xb, csr, rp, deg, inv, (uint4*)a1b);
    k_gemm1<<<PART_BLOCKS, 256, 0, stream>>>((const uint4*)a1b, (const uint4*)xb,
                                             (const uint4*)W1T, b1l, (uint4*)h1b, part);
    k_bnfin<<<1, 128, 0, stream>>>(part, gamma, beta, stats);
    k_agg2 <<<NN / 4, 256, 0, stream>>>((const uint4*)h1b, csr, rp, deg, inv, has, stats,
                                        (uint4*)a2b);
    k_gemm2<<<NT1, 256, 0, stream>>>((const uint4*)a2b, (const uint4*)h1b, stats,
                                     (const uint4*)W2T, b2l, (const uint4*)wfcT, bfc, out);
}

// Round 7
// 432.386 us; speedup vs baseline: 1.7941x; 1.0096x over previous
//
#include <hip/hip_runtime.h>
#include <math.h>

#define NN 100000
#define NE 1600000
#define NB1 391           // ceil(NN/256) scan blocks
#define PART_BLOCKS 768
#define NT1 1563          // ceil(NN/64) M-tiles
#define LDA 136           // padded LDS row stride (ushorts): 272 B, 16B-aligned

typedef float f32x4 __attribute__((ext_vector_type(4)));
typedef float f32x2 __attribute__((ext_vector_type(2)));
typedef short s16x8 __attribute__((ext_vector_type(8)));

// ---- ws layout (4-byte words) ----
#define OFS_DEG8  0                     // int[8][NN] sharded histogram -> base8 after scan3
#define OFS_DEG   (8*NN)                // int[NN]
#define OFS_RP    (9*NN)                // int[NN]
#define OFS_BSUM  (10*NN)
#define OFS_BSCAN (10*NN + 512)
#define OFS_RANK  (10*NN + 1024)        // ushort[NE] -> NE/2 words
#define OFS_CSR   (OFS_RANK + NE/2)
#define OFS_INV   (OFS_CSR + NE)
#define OFS_HAS   (OFS_INV + NN)
#define OFS_XB    (OFS_HAS + NN)        // x bf16 [NN][64]   -> 32*NN words
#define OFS_XB8   (OFS_XB + 32*NN)      // x fp8 [NN][64]    -> 16*NN words
#define OFS_A1B   (OFS_XB8 + 16*NN)     // agg1 bf16 [NN][64]-> 32*NN
#define OFS_H1B   (OFS_A1B + 32*NN)     // h1 bf16 [NN][128] -> 64*NN
#define OFS_H1F8  (OFS_H1B + 64*NN)     // h1 fp8 [NN][128]  -> 32*NN
#define OFS_A2B   (OFS_H1F8 + 32*NN)    // BN'd agg2 bf16 [NN][128] -> 64*NN
#define OFS_W1T   (OFS_A2B + 64*NN)     // [128][128] ush -> 8192 words
#define OFS_W2T   (OFS_W1T + 8192)      // [128][256] ush -> 16384 words
#define OFS_WFCT  (OFS_W2T + 16384)     // [16][128] ush -> 1024 words
#define OFS_STATS (OFS_WFCT + 1024)     // 256
#define OFS_PART  (OFS_STATS + 256)     // 768*256

__device__ __forceinline__ unsigned short f2bf(float f) {
    unsigned u = __float_as_uint(f);
    return (unsigned short)((u + 0x7FFFu + ((u >> 16) & 1u)) >> 16);
}
__device__ __forceinline__ float bfl(unsigned u) { return __uint_as_float(u << 16); }
__device__ __forceinline__ float bfh(unsigned u) { return __uint_as_float(u & 0xFFFF0000u); }

// ---- fp8 e4m3 pack/unpack (HW cvt on gfx950; software fallback) ----
#if __has_builtin(__builtin_amdgcn_cvt_pk_f32_fp8) && __has_builtin(__builtin_amdgcn_cvt_pk_fp8_f32)
__device__ __forceinline__ void acc_fp8x4(unsigned w, float* a) {
    f32x2 lo = __builtin_amdgcn_cvt_pk_f32_fp8((int)w, false);
    f32x2 hi = __builtin_amdgcn_cvt_pk_f32_fp8((int)w, true);
    a[0] += lo[0]; a[1] += lo[1]; a[2] += hi[0]; a[3] += hi[1];
}
__device__ __forceinline__ unsigned pk_fp8x4(float a, float b, float c, float d) {
    int w = __builtin_amdgcn_cvt_pk_fp8_f32(a, b, 0, false);
    w = __builtin_amdgcn_cvt_pk_fp8_f32(c, d, w, true);
    return (unsigned)w;
}
#else
__device__ __forceinline__ float sw_fp82f(unsigned v) {
    unsigned s = (v & 0x80u) << 24;
    unsigned e = (v >> 3) & 15u, m = v & 7u;
    float r = (e == 0) ? ((float)m * 0.001953125f)
                       : __uint_as_float(((e + 120u) << 23) | (m << 20));
    return __uint_as_float(s | __float_as_uint(r));
}
__device__ __forceinline__ void acc_fp8x4(unsigned w, float* a) {
    a[0] += sw_fp82f(w & 255u); a[1] += sw_fp82f((w >> 8) & 255u);
    a[2] += sw_fp82f((w >> 16) & 255u); a[3] += sw_fp82f(w >> 24);
}
__device__ __forceinline__ unsigned sw_f2fp8(float f) {
    unsigned b = __float_as_uint(f);
    unsigned s = (b >> 24) & 0x80u;
    float af = fabsf(f);
    if (af < 0.0009765625f) return s;
    if (af >= 448.f) return s | 0x7Eu;
    int e = (int)((b >> 23) & 255u) - 127;
    if (e < -6) {
        int q = (int)rintf(af * 512.f);
        return s | (unsigned)q;
    }
    unsigned man = b & 0x7FFFFFu;
    unsigned r = (man + 0x7FFFFu + ((man >> 20) & 1u)) >> 20;
    unsigned enc = ((unsigned)(e + 7) << 3) + r;
    if (enc >= 0x7Fu) enc = 0x7Eu;
    return s | enc;
}
__device__ __forceinline__ unsigned pk_fp8x4(float a, float b, float c, float d) {
    return sw_f2fp8(a) | (sw_f2fp8(b) << 8) | (sw_f2fp8(c) << 16) | (sw_f2fp8(d) << 24);
}
#endif

// ---------------- cast x -> bf16 + fp8 ----------------
__global__ void k_cast(const float4* __restrict__ x4, uint2* __restrict__ xb,
                       unsigned* __restrict__ xb8) {
    int i = blockIdx.x * 256 + threadIdx.x;  // i < NN*16
    float4 v = x4[i];
    uint2 o;
    o.x = (unsigned)f2bf(v.x) | ((unsigned)f2bf(v.y) << 16);
    o.y = (unsigned)f2bf(v.z) | ((unsigned)f2bf(v.w) << 16);
    xb[i] = o;
    xb8[i] = pk_fp8x4(v.x, v.y, v.z, v.w);
}

// ---------------- weight prep: transposed bf16 ----------------
__global__ void k_prep(const float* __restrict__ w1l, const float* __restrict__ w1r,
                       const float* __restrict__ w2l, const float* __restrict__ w2r,
                       const float* __restrict__ wfc,
                       unsigned short* __restrict__ W1T, unsigned short* __restrict__ W2T,
                       unsigned short* __restrict__ wfcT) {
    int b = blockIdx.x, t = threadIdx.x;  // 128 threads
    if (b < 128) {
        int n = b, k = t;
        float v = (k < 64) ? w1l[k * 128 + n] : w1r[(k - 64) * 128 + n];
        W1T[n * 128 + k] = f2bf(v);
    } else if (b < 256) {
        int n = b - 128;
        W2T[n * 256 + t] = f2bf(w2l[t * 128 + n]);
        W2T[n * 256 + 128 + t] = f2bf(w2r[t * 128 + n]);
    } else {
        int o = b - 256;
        wfcT[o * 128 + t] = f2bf(wfc[t * 16 + o]);
    }
}

// ---------------- CSR build: sharded rank histogram ----------------
__global__ void k_rank(const int* __restrict__ ei, int* __restrict__ deg8,
                       unsigned short* __restrict__ rank) {
    int e = blockIdx.x * 256 + threadIdx.x;
    int c = blockIdx.x & 7;
    int d = ei[NE + e];
    int r = atomicAdd(&deg8[c * NN + d], 1);
    rank[e] = (unsigned short)r;
}

__global__ void k_scan1(const int* __restrict__ deg8, int* __restrict__ deg,
                        int* __restrict__ bsum) {
    __shared__ int sb[256];
    int t = threadIdx.x;
    int i = blockIdx.x * 256 + t;
    int s = 0;
    if (i < NN) {
#pragma unroll
        for (int c = 0; c < 8; c++) s += deg8[c * NN + i];
        deg[i] = s;
    }
    sb[t] = s;
    __syncthreads();
    for (int off = 128; off > 0; off >>= 1) {
        if (t < off) sb[t] += sb[t + off];
        __syncthreads();
    }
    if (t == 0) bsum[blockIdx.x] = sb[0];
}

__global__ void k_scan2(const int* __restrict__ bsum, int* __restrict__ bscan) {
    __shared__ int sb[512];
    int t = threadIdx.x;
    int v = (t < NB1) ? bsum[t] : 0;
    sb[t] = v;
    __syncthreads();
    for (int off = 1; off < 512; off <<= 1) {
        int u = (t >= off) ? sb[t - off] : 0;
        __syncthreads();
        sb[t] += u;
        __syncthreads();
    }
    if (t < NB1) bscan[t] = sb[t] - v;   // exclusive
}

__global__ void k_scan3(const int* __restrict__ deg, const int* __restrict__ bscan,
                        int* __restrict__ rp, int* __restrict__ base8,
                        float* __restrict__ inv, float* __restrict__ has) {
    __shared__ int sb[256];
    int t = threadIdx.x;
    int i = blockIdx.x * 256 + t;
    int d = (i < NN) ? deg[i] : 0;
    sb[t] = d;
    __syncthreads();
    for (int off = 1; off < 256; off <<= 1) {
        int u = (t >= off) ? sb[t - off] : 0;
        __syncthreads();
        sb[t] += u;
        __syncthreads();
    }
    if (i < NN) {
        int start = sb[t] - d + bscan[blockIdx.x];
        rp[i] = start;
        inv[i] = 1.0f / fmaxf((float)d, 1.0f);
        has[i] = (d > 0) ? 1.0f : 0.0f;
        int run = start;
#pragma unroll
        for (int c = 0; c < 8; c++) {
            int dc = base8[c * NN + i];
            base8[c * NN + i] = run;
            run += dc;
        }
    }
}

__global__ void k_fill(const int* __restrict__ ei, const unsigned short* __restrict__ rank,
                       const int* __restrict__ base8, int* __restrict__ csr) {
    int e = blockIdx.x * 256 + threadIdx.x;
    int c = blockIdx.x & 7;
    int d = ei[NE + e];
    int s = ei[e];
    int pos = base8[c * NN + d] + (int)rank[e];
    __builtin_nontemporal_store(s, &csr[pos]);
}

// ---------------- gather layer 1 (fp8): agg1b[n] = bf16(mean x[s]) ----------------
// 1 node/wave; 8 edge-chains x 8 lanes x 8B (row = 64 fp8)
__global__ __launch_bounds__(256) void k_agg1(
    const uint2* __restrict__ xb8, const int* __restrict__ csr,
    const int* __restrict__ rp, const int* __restrict__ deg,
    const float* __restrict__ inv, uint4* __restrict__ agg1b) {
    int t = threadIdx.x;
    int lane = t & 63;
    int chain = lane >> 3, f = lane & 7;
    int node = blockIdx.x * 4 + (t >> 6);
    int len = deg[node];
    const int* cp = csr + rp[node];
    float a[8] = {0, 0, 0, 0, 0, 0, 0, 0};
    for (int j = chain; j < len; j += 8) {
        int s = cp[j];
        uint2 u = xb8[s * 8 + f];
        acc_fp8x4(u.x, a);
        acc_fp8x4(u.y, a + 4);
    }
#pragma unroll
    for (int k = 0; k < 8; k++) {
        a[k] += __shfl_xor(a[k], 8);
        a[k] += __shfl_xor(a[k], 16);
        a[k] += __shfl_xor(a[k], 32);
    }
    if (lane < 8) {
        float ic = inv[node];
        uint4 o;
        o.x = (unsigned)f2bf(a[0] * ic) | ((unsigned)f2bf(a[1] * ic) << 16);
        o.y = (unsigned)f2bf(a[2] * ic) | ((unsigned)f2bf(a[3] * ic) << 16);
        o.z = (unsigned)f2bf(a[4] * ic) | ((unsigned)f2bf(a[5] * ic) << 16);
        o.w = (unsigned)f2bf(a[6] * ic) | ((unsigned)f2bf(a[7] * ic) << 16);
        agg1b[node * 8 + f] = o;
    }
}

// ---------------- gather layer 2 (fp8) + BN fold ----------------
// 1 node/wave; 8 edge-chains x 8 lanes x 16B (row = 128 fp8)
__global__ __launch_bounds__(256) void k_agg2(
    const uint4* __restrict__ h1f8, const int* __restrict__ csr,
    const int* __restrict__ rp, const int* __restrict__ deg,
    const float* __restrict__ inv, const float* __restrict__ has,
    const float* __restrict__ stats, uint4* __restrict__ a2b) {
    int t = threadIdx.x;
    int lane = t & 63;
    int chain = lane >> 3, f = lane & 7;
    int node = blockIdx.x * 4 + (t >> 6);
    int len = deg[node];
    const int* cp = csr + rp[node];
    float a[16];
#pragma unroll
    for (int k = 0; k < 16; k++) a[k] = 0.f;
    for (int j = chain; j < len; j += 8) {
        int s = cp[j];
        uint4 u = h1f8[s * 8 + f];
        acc_fp8x4(u.x, a);
        acc_fp8x4(u.y, a + 4);
        acc_fp8x4(u.z, a + 8);
        acc_fp8x4(u.w, a + 12);
    }
#pragma unroll
    for (int k = 0; k < 16; k++) {
        a[k] += __shfl_xor(a[k], 8);
        a[k] += __shfl_xor(a[k], 16);
        a[k] += __shfl_xor(a[k], 32);
    }
    if (lane < 8) {
        float ic = inv[node], hv = has[node];
        const float4* sc4 = (const float4*)stats;
        const float4* sh4 = (const float4*)(stats + 128);
        float v[16];
#pragma unroll
        for (int q = 0; q < 4; q++) {
            float4 sc = sc4[f * 4 + q];
            float4 sh = sh4[f * 4 + q];
            v[q * 4 + 0] = a[q * 4 + 0] * ic * sc.x + sh.x * hv;
            v[q * 4 + 1] = a[q * 4 + 1] * ic * sc.y + sh.y * hv;
            v[q * 4 + 2] = a[q * 4 + 2] * ic * sc.z + sh.z * hv;
            v[q * 4 + 3] = a[q * 4 + 3] * ic * sc.w + sh.w * hv;
        }
        uint4 o0, o1;
        o0.x = (unsigned)f2bf(v[0]) | ((unsigned)f2bf(v[1]) << 16);
        o0.y = (unsigned)f2bf(v[2]) | ((unsigned)f2bf(v[3]) << 16);
        o0.z = (unsigned)f2bf(v[4]) | ((unsigned)f2bf(v[5]) << 16);
        o0.w = (unsigned)f2bf(v[6]) | ((unsigned)f2bf(v[7]) << 16);
        o1.x = (unsigned)f2bf(v[8]) | ((unsigned)f2bf(v[9]) << 16);
        o1.y = (unsigned)f2bf(v[10]) | ((unsigned)f2bf(v[11]) << 16);
        o1.z = (unsigned)f2bf(v[12]) | ((unsigned)f2bf(v[13]) << 16);
        o1.w = (unsigned)f2bf(v[14]) | ((unsigned)f2bf(v[15]) << 16);
        a2b[node * 16 + f * 2] = o0;
        a2b[node * 16 + f * 2 + 1] = o1;
    }
}

// ---------------- layer 1 MFMA: C=[agg1|x]@[w1l;w1r]+b1l; L2norm; relu; BN stats ----
__global__ __launch_bounds__(256, 3) void k_gemm1(
    const uint4* __restrict__ agg1b, const uint4* __restrict__ xb,
    const uint4* __restrict__ W1T, const float* __restrict__ b1l,
    uint4* __restrict__ h1b, uint4* __restrict__ h1f8, float* __restrict__ part) {
    __shared__ unsigned short Wsm[128 * LDA];  // 34816 B
    __shared__ unsigned short Asm[64 * LDA];   // 17408 B
    __shared__ float cs[128], cq[128];
    const int t = threadIdx.x;
    const int w = t >> 6, lane = t & 63, quad = lane >> 4, l15 = lane & 15;
    if (t < 128) { cs[t] = 0.f; cq[t] = 0.f; }
    // stage W1T once (row=256B=16 uint4)
    {
        int r = t >> 1, h = t & 1;
#pragma unroll
        for (int i = 0; i < 8; i++) {
            uint4 v = W1T[r * 16 + h * 8 + i];
            *(uint4*)&Wsm[r * LDA + h * 64 + i * 8] = v;
        }
    }
    float bias[8];
#pragma unroll
    for (int nt = 0; nt < 8; nt++) bias[nt] = b1l[nt * 16 + l15];
    float colsum[8] = {0, 0, 0, 0, 0, 0, 0, 0};
    float colsq[8]  = {0, 0, 0, 0, 0, 0, 0, 0};

    for (int g = blockIdx.x; g < NT1; g += gridDim.x) {
        const int base = g * 64;
        const int valid = (NN - base < 64) ? (NN - base) : 64;
        __syncthreads();  // prev readback / W staging done
        {   // stage A: row m = [agg1b row m (128B) | xb row m (128B)]
            int m = t >> 2, p = t & 3;
            bool ok = m < valid;
            int gm = base + m;
            const uint4* src = (p < 2) ? agg1b : xb;
            int pc = p & 1;
#pragma unroll
            for (int i = 0; i < 4; i++) {
                uint4 v = ok ? src[gm * 8 + pc * 4 + i] : make_uint4(0, 0, 0, 0);
                *(uint4*)&Asm[m * LDA + p * 32 + i * 8] = v;
            }
        }
        __syncthreads();
        f32x4 acc[8];
#pragma unroll
        for (int nt = 0; nt < 8; nt++) acc[nt] = (f32x4){bias[nt], bias[nt], bias[nt], bias[nt]};
#pragma unroll
        for (int kc = 0; kc < 4; kc++) {
            s16x8 af = *(const s16x8*)&Asm[(16 * w + l15) * LDA + kc * 32 + quad * 8];
#pragma unroll
            for (int nt = 0; nt < 8; nt++) {
                s16x8 bf = *(const s16x8*)&Wsm[(nt * 16 + l15) * LDA + kc * 32 + quad * 8];
                acc[nt] = __builtin_amdgcn_mfma_f32_16x16x32_bf16(af, bf, acc[nt], 0, 0, 0);
            }
        }
        // epilogue: norm+relu+stats, write h1 bf16 into Asm (own rows)
        float ssr[4] = {0, 0, 0, 0};
#pragma unroll
        for (int nt = 0; nt < 8; nt++)
#pragma unroll
            for (int r = 0; r < 4; r++) ssr[r] += acc[nt][r] * acc[nt][r];
#pragma unroll
        for (int r = 0; r < 4; r++) {
            ssr[r] += __shfl_xor(ssr[r], 1); ssr[r] += __shfl_xor(ssr[r], 2);
            ssr[r] += __shfl_xor(ssr[r], 4); ssr[r] += __shfl_xor(ssr[r], 8);
        }
#pragma unroll
        for (int r = 0; r < 4; r++) {
            int mrow = 16 * w + quad * 4 + r;
            float iv = 1.0f / fmaxf(sqrtf(ssr[r]), 1e-12f);
            bool okr = mrow < valid;
#pragma unroll
            for (int nt = 0; nt < 8; nt++) {
                float v = fmaxf(acc[nt][r] * iv, 0.f);
                if (!okr) v = 0.f;
                colsum[nt] += v;
                colsq[nt] += v * v;
                Asm[mrow * LDA + nt * 16 + l15] = f2bf(v);
            }
        }
        __syncthreads();
        {   // coalesced h1b store (row=256B=16 uint4) + fp8 shadow (row=128B=8 uint4)
            int m = t >> 2, p = t & 3;
            if (m < valid) {
                int gm = base + m;
                unsigned w8[8];
#pragma unroll
                for (int i = 0; i < 4; i++) {
                    uint4 v = *(const uint4*)&Asm[m * LDA + p * 32 + i * 8];
                    h1b[gm * 16 + p * 4 + i] = v;
                    float f0 = bfl(v.x), f1 = bfh(v.x), f2 = bfl(v.y), f3 = bfh(v.y);
                    float f4 = bfl(v.z), f5 = bfh(v.z), f6 = bfl(v.w), f7 = bfh(v.w);
                    w8[i * 2] = pk_fp8x4(f0, f1, f2, f3);
                    w8[i * 2 + 1] = pk_fp8x4(f4, f5, f6, f7);
                }
                h1f8[gm * 8 + p * 2] = make_uint4(w8[0], w8[1], w8[2], w8[3]);
                h1f8[gm * 8 + p * 2 + 1] = make_uint4(w8[4], w8[5], w8[6], w8[7]);
            }
        }
    }
    __syncthreads();
#pragma unroll
    for (int nt = 0; nt < 8; nt++) {
        atomicAdd(&cs[nt * 16 + l15], colsum[nt]);
        atomicAdd(&cq[nt * 16 + l15], colsq[nt]);
    }
    __syncthreads();
    if (t < 128) {
        part[blockIdx.x * 256 + t] = cs[t];
        part[blockIdx.x * 256 + 128 + t] = cq[t];
    }
}

// ---------------- BN finalize ----------------
__global__ void k_bnfin(const float* __restrict__ part, const float* __restrict__ gamma,
                        const float* __restrict__ beta, float* __restrict__ stats) {
    int t = threadIdx.x;  // 128
    float s = 0.f, q = 0.f;
    for (int b = 0; b < PART_BLOCKS; b++) {
        s += part[b * 256 + t];
        q += part[b * 256 + 128 + t];
    }
    float mean = s / (float)NN;
    float var = q / (float)NN - mean * mean;
    float sc = gamma[t] * rsqrtf(var + 1e-5f);
    stats[t] = sc;
    stats[128 + t] = beta[t] - mean * sc;
}

// ---------------- layer 2 MFMA (K=256) + L2norm + FC ----------------
__global__ __launch_bounds__(256, 3) void k_gemm2(
    const uint4* __restrict__ a2b, const uint4* __restrict__ h1b,
    const float* __restrict__ stats,
    const uint4* __restrict__ W2T, const float* __restrict__ b2l,
    const uint4* __restrict__ wfcT, const float* __restrict__ bfc,
    float* __restrict__ out) {
    __shared__ unsigned short Wsm[128 * LDA];
    __shared__ unsigned short Asm[64 * LDA];
    const int t = threadIdx.x;
    const int w = t >> 6, lane = t & 63, quad = lane >> 4, l15 = lane & 15;
    const int base = blockIdx.x * 64;
    const int valid = (NN - base < 64) ? (NN - base) : 64;

    f32x4 acc[8];
#pragma unroll
    for (int nt = 0; nt < 8; nt++) {
        float b = b2l[nt * 16 + l15];
        acc[nt] = (f32x4){b, b, b, b};
    }

#pragma unroll
    for (int phase = 0; phase < 2; phase++) {
        if (phase) __syncthreads();  // prev MFMA reads done
        {   // stage W half (W2T row = 512B = 32 uint4)
            int r = t >> 1, h = t & 1;
#pragma unroll
            for (int i = 0; i < 8; i++) {
                uint4 v = W2T[r * 32 + phase * 16 + h * 8 + i];
                *(uint4*)&Wsm[r * LDA + h * 64 + i * 8] = v;
            }
        }
        {   // stage A half
            int m = t >> 2, p = t & 3;
            bool ok = m < valid;
            int gm = base + m;
            if (phase == 0) {
#pragma unroll
                for (int i = 0; i < 4; i++) {
                    uint4 v = ok ? a2b[gm * 16 + p * 4 + i] : make_uint4(0, 0, 0, 0);
                    *(uint4*)&Asm[m * LDA + p * 32 + i * 8] = v;
                }
            } else {
                const float4* sc4 = (const float4*)stats;
                const float4* sh4 = (const float4*)(stats + 128);
#pragma unroll
                for (int i = 0; i < 4; i++) {
                    uint4 v = make_uint4(0, 0, 0, 0);
                    if (ok) {
                        v = h1b[gm * 16 + p * 4 + i];
                        int c4 = (p * 32 + i * 8) >> 2;
                        float4 s0 = sc4[c4], s1 = sc4[c4 + 1];
                        float4 t0 = sh4[c4], t1 = sh4[c4 + 1];
                        float e0 = bfl(v.x) * s0.x + t0.x, e1 = bfh(v.x) * s0.y + t0.y;
                        float e2 = bfl(v.y) * s0.z + t0.z, e3 = bfh(v.y) * s0.w + t0.w;
                        float e4 = bfl(v.z) * s1.x + t1.x, e5 = bfh(v.z) * s1.y + t1.y;
                        float e6 = bfl(v.w) * s1.z + t1.z, e7 = bfh(v.w) * s1.w + t1.w;
                        v.x = (unsigned)f2bf(e0) | ((unsigned)f2bf(e1) << 16);
                        v.y = (unsigned)f2bf(e2) | ((unsigned)f2bf(e3) << 16);
                        v.z = (unsigned)f2bf(e4) | ((unsigned)f2bf(e5) << 16);
                        v.w = (unsigned)f2bf(e6) | ((unsigned)f2bf(e7) << 16);
                    }
                    *(uint4*)&Asm[m * LDA + p * 32 + i * 8] = v;
                }
            }
        }
        __syncthreads();
#pragma unroll
        for (int kc = 0; kc < 4; kc++) {
            s16x8 af = *(const s16x8*)&Asm[(16 * w + l15) * LDA + kc * 32 + quad * 8];
#pragma unroll
            for (int nt = 0; nt < 8; nt++) {
                s16x8 bf = *(const s16x8*)&Wsm[(nt * 16 + l15) * LDA + kc * 32 + quad * 8];
                acc[nt] = __builtin_amdgcn_mfma_f32_16x16x32_bf16(af, bf, acc[nt], 0, 0, 0);
            }
        }
    }
    // epilogue: L2 norm (no relu), h2 -> Asm (own rows)
    float ssr[4] = {0, 0, 0, 0};
#pragma unroll
    for (int nt = 0; nt < 8; nt++)
#pragma unroll
        for (int r = 0; r < 4; r++) ssr[r] += acc[nt][r] * acc[nt][r];
#pragma unroll
    for (int r = 0; r < 4; r++) {
        ssr[r] += __shfl_xor(ssr[r], 1); ssr[r] += __shfl_xor(ssr[r], 2);
        ssr[r] += __shfl_xor(ssr[r], 4); ssr[r] += __shfl_xor(ssr[r], 8);
    }
#pragma unroll
    for (int r = 0; r < 4; r++) {
        int mrow = 16 * w + quad * 4 + r;
        float iv = 1.0f / fmaxf(sqrtf(ssr[r]), 1e-12f);
#pragma unroll
        for (int nt = 0; nt < 8; nt++) {
            Asm[mrow * LDA + nt * 16 + l15] = f2bf(acc[nt][r] * iv);
        }
    }
    __syncthreads();  // h2 writes + all W reads done
    // stage wfcT (16 rows x 256B = 16 uint4/row)
    if (t < 64) {
        int n = t >> 2, p = t & 3;
#pragma unroll
        for (int i = 0; i < 4; i++) {
            uint4 v = wfcT[n * 16 + p * 4 + i];
            *(uint4*)&Wsm[n * LDA + p * 32 + i * 8] = v;
        }
    }
    __syncthreads();
    // FC: 16x16 tile per wave, K=128
    f32x4 a2;
    {
        float b = bfc[l15];
        a2 = (f32x4){b, b, b, b};
    }
#pragma unroll
    for (int kc = 0; kc < 4; kc++) {
        s16x8 af = *(const s16x8*)&Asm[(16 * w + l15) * LDA + kc * 32 + quad * 8];
        s16x8 bf = *(const s16x8*)&Wsm[l15 * LDA + kc * 32 + quad * 8];
        a2 = __builtin_amdgcn_mfma_f32_16x16x32_bf16(af, bf, a2, 0, 0, 0);
    }
#pragma unroll
    for (int r = 0; r < 4; r++) {
        int mrow = 16 * w + quad * 4 + r;
        if (mrow < valid) out[(base + mrow) * 16 + l15] = a2[r];
    }
}

extern "C" void kernel_launch(void* const* d_in, const int* in_sizes, int n_in,
                              void* d_out, int out_size, void* d_ws, size_t ws_size,
                              hipStream_t stream) {
    const float* x     = (const float*)d_in[0];
    const int*   ei    = (const int*)d_in[1];
    const float* w1l   = (const float*)d_in[2];
    const float* b1l   = (const float*)d_in[3];
    const float* w1r   = (const float*)d_in[4];
    const float* gamma = (const float*)d_in[5];
    const float* beta  = (const float*)d_in[6];
    const float* w2l   = (const float*)d_in[7];
    const float* b2l   = (const float*)d_in[8];
    const float* w2r   = (const float*)d_in[9];
    const float* wfc   = (const float*)d_in[10];
    const float* bfc   = (const float*)d_in[11];
    float* out = (float*)d_out;

    float* W = (float*)d_ws;
    int* deg8  = (int*)(W + OFS_DEG8);
    int* deg   = (int*)(W + OFS_DEG);
    int* rp    = (int*)(W + OFS_RP);
    int* bsum  = (int*)(W + OFS_BSUM);
    int* bscan = (int*)(W + OFS_BSCAN);
    unsigned short* rank = (unsigned short*)(W + OFS_RANK);
    int* csr   = (int*)(W + OFS_CSR);
    float* inv   = W + OFS_INV;
    float* has   = W + OFS_HAS;
    unsigned* xb   = (unsigned*)(W + OFS_XB);
    unsigned* xb8  = (unsigned*)(W + OFS_XB8);
    unsigned* a1b  = (unsigned*)(W + OFS_A1B);
    unsigned* h1b  = (unsigned*)(W + OFS_H1B);
    unsigned* h1f8 = (unsigned*)(W + OFS_H1F8);
    unsigned* a2b  = (unsigned*)(W + OFS_A2B);
    unsigned short* W1T  = (unsigned short*)(W + OFS_W1T);
    unsigned short* W2T  = (unsigned short*)(W + OFS_W2T);
    unsigned short* wfcT = (unsigned short*)(W + OFS_WFCT);
    float* stats = W + OFS_STATS;
    float* part  = W + OFS_PART;

    hipMemsetAsync(deg8, 0, 8 * NN * sizeof(int), stream);

    k_cast<<<NN * 16 / 256, 256, 0, stream>>>((const float4*)x, (uint2*)xb, xb8);
    k_prep<<<272, 128, 0, stream>>>(w1l, w1r, w2l, w2r, wfc, W1T, W2T, wfcT);
    k_rank <<<NE / 256, 256, 0, stream>>>(ei, deg8, rank);
    k_scan1<<<NB1, 256, 0, stream>>>(deg8, deg, bsum);
    k_scan2<<<1, 512, 0, stream>>>(bsum, bscan);
    k_scan3<<<NB1, 256, 0, stream>>>(deg, bscan, rp, deg8, inv, has);
    k_fill <<<NE / 256, 256, 0, stream>>>(ei, rank, deg8, csr);

    k_agg1 <<<NN / 4, 256, 0, stream>>>((const uint2*)xb8, csr, rp, deg, inv, (uint4*)a1b);
    k_gemm1<<<PART_BLOCKS, 256, 0, stream>>>((const uint4*)a1b, (const uint4*)xb,
                                             (const uint4*)W1T, b1l, (uint4*)h1b,
                                             (uint4*)h1f8, part);
    k_bnfin<<<1, 128, 0, stream>>>(part, gamma, beta, stats);
    k_agg2 <<<NN / 4, 256, 0, stream>>>((const uint4*)h1f8, csr, rp, deg, inv, has, stats,
                                        (uint4*)a2b);
    k_gemm2<<<NT1, 256, 0, stream>>>((const uint4*)a2b, (const uint4*)h1b, stats,
                                     (const uint4*)W2T, b2l, (const uint4*)wfcT, bfc, out);
}

// Round 8
// 421.032 us; speedup vs baseline: 1.8425x; 1.0270x over previous
//
#include <hip/hip_runtime.h>
#include <math.h>

#define NN 100000
#define NE 1600000
#define NB1 391           // ceil(NN/256) scan blocks
#define PART_BLOCKS 768
#define NT1 1563          // ceil(NN/64) M-tiles
#define LDA 136           // padded LDS row stride (ushorts): 272 B, 16B-aligned

typedef float f32x4 __attribute__((ext_vector_type(4)));
typedef float f32x2 __attribute__((ext_vector_type(2)));
typedef short s16x8 __attribute__((ext_vector_type(8)));

// ---- ws layout (4-byte words) ----
#define OFS_DEG8  0                     // int[8][NN] sharded histogram -> base8 after scan3
#define OFS_DEG   (8*NN)                // int[NN]
#define OFS_RP    (9*NN)                // int[NN]
#define OFS_BSUM  (10*NN)
#define OFS_RANK  (10*NN + 1024)        // ushort[NE] -> NE/2 words
#define OFS_CSR   (OFS_RANK + NE/2)
#define OFS_INV   (OFS_CSR + NE)
#define OFS_HAS   (OFS_INV + NN)
#define OFS_XB    (OFS_HAS + NN)        // x bf16 [NN][64]   -> 32*NN words
#define OFS_XB8   (OFS_XB + 32*NN)      // x fp8 [NN][64]    -> 16*NN words
#define OFS_A1B   (OFS_XB8 + 16*NN)     // agg1 bf16 [NN][64]-> 32*NN
#define OFS_H1B   (OFS_A1B + 32*NN)     // h1 bf16 [NN][128] -> 64*NN
#define OFS_H1F8  (OFS_H1B + 64*NN)     // h1 fp8 PERMUTED [NN][128] -> 32*NN
#define OFS_A2B   (OFS_H1F8 + 32*NN)    // BN'd agg2 bf16 PERMUTED [NN][128] -> 64*NN
#define OFS_W1T   (OFS_A2B + 64*NN)     // [128][128] ush -> 8192 words
#define OFS_W2T   (OFS_W1T + 8192)      // [128][256] ush (lin_l K-rows permuted) -> 16384
#define OFS_WFCT  (OFS_W2T + 16384)     // [16][128] ush -> 1024 words
#define OFS_STATS (OFS_WFCT + 1024)     // 512: [sc 128][sh 128][sc' 128][sh' 128]
#define OFS_PART  (OFS_STATS + 512)     // 768*256

// col permutation: c' = l15*8 + nt  <->  c = nt*16 + l15  (P(c') = (c'&7)*16 + (c'>>3))

__device__ __forceinline__ unsigned short f2bf(float f) {
    unsigned u = __float_as_uint(f);
    return (unsigned short)((u + 0x7FFFu + ((u >> 16) & 1u)) >> 16);
}
__device__ __forceinline__ float bfl(unsigned u) { return __uint_as_float(u << 16); }
__device__ __forceinline__ float bfh(unsigned u) { return __uint_as_float(u & 0xFFFF0000u); }

// ---- fp8 e4m3 pack/unpack (HW cvt on gfx950; software fallback) ----
#if __has_builtin(__builtin_amdgcn_cvt_pk_f32_fp8) && __has_builtin(__builtin_amdgcn_cvt_pk_fp8_f32)
__device__ __forceinline__ f32x2 cvt2_lo(unsigned w) {
    return __builtin_amdgcn_cvt_pk_f32_fp8((int)w, false);
}
__device__ __forceinline__ f32x2 cvt2_hi(unsigned w) {
    return __builtin_amdgcn_cvt_pk_f32_fp8((int)w, true);
}
__device__ __forceinline__ unsigned pk_fp8x4(float a, float b, float c, float d) {
    int w = __builtin_amdgcn_cvt_pk_fp8_f32(a, b, 0, false);
    w = __builtin_amdgcn_cvt_pk_fp8_f32(c, d, w, true);
    return (unsigned)w;
}
#else
__device__ __forceinline__ float sw_fp82f(unsigned v) {
    unsigned s = (v & 0x80u) << 24;
    unsigned e = (v >> 3) & 15u, m = v & 7u;
    float r = (e == 0) ? ((float)m * 0.001953125f)
                       : __uint_as_float(((e + 120u) << 23) | (m << 20));
    return __uint_as_float(s | __float_as_uint(r));
}
__device__ __forceinline__ f32x2 cvt2_lo(unsigned w) {
    return (f32x2){sw_fp82f(w & 255u), sw_fp82f((w >> 8) & 255u)};
}
__device__ __forceinline__ f32x2 cvt2_hi(unsigned w) {
    return (f32x2){sw_fp82f((w >> 16) & 255u), sw_fp82f(w >> 24)};
}
__device__ __forceinline__ unsigned sw_f2fp8(float f) {
    unsigned b = __float_as_uint(f);
    unsigned s = (b >> 24) & 0x80u;
    float af = fabsf(f);
    if (af < 0.0009765625f) return s;
    if (af >= 448.f) return s | 0x7Eu;
    int e = (int)((b >> 23) & 255u) - 127;
    if (e < -6) {
        int q = (int)rintf(af * 512.f);
        return s | (unsigned)q;
    }
    unsigned man = b & 0x7FFFFFu;
    unsigned r = (man + 0x7FFFFu + ((man >> 20) & 1u)) >> 20;
    unsigned enc = ((unsigned)(e + 7) << 3) + r;
    if (enc >= 0x7Fu) enc = 0x7Eu;
    return s | enc;
}
__device__ __forceinline__ unsigned pk_fp8x4(float a, float b, float c, float d) {
    return sw_f2fp8(a) | (sw_f2fp8(b) << 8) | (sw_f2fp8(c) << 16) | (sw_f2fp8(d) << 24);
}
#endif

// ---------------- init: cast x -> bf16+fp8, weights -> transposed bf16 ----------------
#define CAST_BLOCKS 6250   // NN*16/256
#define PREP_BLOCKS 200    // (16384+32768+2048)/256
__global__ void k_init(const float4* __restrict__ x4, uint2* __restrict__ xb,
                       unsigned* __restrict__ xb8,
                       const float* __restrict__ w1l, const float* __restrict__ w1r,
                       const float* __restrict__ w2l, const float* __restrict__ w2r,
                       const float* __restrict__ wfc,
                       unsigned short* __restrict__ W1T, unsigned short* __restrict__ W2T,
                       unsigned short* __restrict__ wfcT) {
    int b = blockIdx.x, t = threadIdx.x;
    if (b < CAST_BLOCKS) {
        int i = b * 256 + t;
        float4 v = x4[i];
        uint2 o;
        o.x = (unsigned)f2bf(v.x) | ((unsigned)f2bf(v.y) << 16);
        o.y = (unsigned)f2bf(v.z) | ((unsigned)f2bf(v.w) << 16);
        xb[i] = o;
        xb8[i] = pk_fp8x4(v.x, v.y, v.z, v.w);
        return;
    }
    int u = (b - CAST_BLOCKS) * 256 + t;
    if (u < 16384) {
        int n = u >> 7, k = u & 127;
        float v = (k < 64) ? w1l[k * 128 + n] : w1r[(k - 64) * 128 + n];
        W1T[u] = f2bf(v);
    } else if (u < 16384 + 32768) {
        int u2 = u - 16384;
        int n = u2 >> 8, kk = u2 & 255;
        float v;
        if (kk < 128) {
            int pk = (kk & 7) * 16 + (kk >> 3);   // permuted lin_l K-row
            v = w2l[pk * 128 + n];
        } else {
            v = w2r[(kk - 128) * 128 + n];
        }
        W2T[u2] = f2bf(v);
    } else {
        int u3 = u - 16384 - 32768;
        int o = u3 >> 7, k = u3 & 127;
        wfcT[u3] = f2bf(wfc[k * 16 + o]);
    }
}

// ---------------- CSR build: sharded rank histogram ----------------
__global__ void k_rank(const int* __restrict__ ei, int* __restrict__ deg8,
                       unsigned short* __restrict__ rank) {
    int e = blockIdx.x * 256 + threadIdx.x;
    int c = blockIdx.x & 7;
    int d = ei[NE + e];
    int r = atomicAdd(&deg8[c * NN + d], 1);
    rank[e] = (unsigned short)r;
}

__global__ void k_scan1(const int* __restrict__ deg8, int* __restrict__ deg,
                        int* __restrict__ bsum) {
    __shared__ int sb[256];
    int t = threadIdx.x;
    int i = blockIdx.x * 256 + t;
    int s = 0;
    if (i < NN) {
#pragma unroll
        for (int c = 0; c < 8; c++) s += deg8[c * NN + i];
        deg[i] = s;
    }
    sb[t] = s;
    __syncthreads();
    for (int off = 128; off > 0; off >>= 1) {
        if (t < off) sb[t] += sb[t + off];
        __syncthreads();
    }
    if (t == 0) bsum[blockIdx.x] = sb[0];
}

// per-node start offsets (self-computes block prefix of bsum); deg8 -> base8 in place
__global__ void k_scan3(const int* __restrict__ deg, const int* __restrict__ bsum,
                        int* __restrict__ rp, int* __restrict__ base8,
                        float* __restrict__ inv, float* __restrict__ has) {
    __shared__ int sb[256];
    __shared__ int sbase;
    int t = threadIdx.x;
    // redundant per-block exclusive prefix over bsum
    int partial = 0;
    for (int b = t; b < blockIdx.x; b += 256) partial += bsum[b];
    sb[t] = partial;
    __syncthreads();
    for (int off = 128; off > 0; off >>= 1) {
        if (t < off) sb[t] += sb[t + off];
        __syncthreads();
    }
    if (t == 0) sbase = sb[0];
    __syncthreads();
    int blkbase = sbase;
    __syncthreads();
    int i = blockIdx.x * 256 + t;
    int d = (i < NN) ? deg[i] : 0;
    sb[t] = d;
    __syncthreads();
    for (int off = 1; off < 256; off <<= 1) {
        int u = (t >= off) ? sb[t - off] : 0;
        __syncthreads();
        sb[t] += u;
        __syncthreads();
    }
    if (i < NN) {
        int start = sb[t] - d + blkbase;
        rp[i] = start;
        inv[i] = 1.0f / fmaxf((float)d, 1.0f);
        has[i] = (d > 0) ? 1.0f : 0.0f;
        int run = start;
#pragma unroll
        for (int c = 0; c < 8; c++) {
            int dc = base8[c * NN + i];
            base8[c * NN + i] = run;
            run += dc;
        }
    }
}

__global__ void k_fill(const int* __restrict__ ei, const unsigned short* __restrict__ rank,
                       const int* __restrict__ base8, int* __restrict__ csr) {
    int e = blockIdx.x * 256 + threadIdx.x;
    int c = blockIdx.x & 7;
    int d = ei[NE + e];
    int s = ei[e];
    int pos = base8[c * NN + d] + (int)rank[e];
    __builtin_nontemporal_store(s, &csr[pos]);
}

// ---------------- gather layer 1 (fp8): agg1b[n] = bf16(mean x[s]) ----------------
// 1 node/wave; 8 edge-chains x 8 lanes x 8B; packed f32x2 accumulate; index prefetch
__global__ __launch_bounds__(256) void k_agg1(
    const uint2* __restrict__ xb8, const int* __restrict__ csr,
    const int* __restrict__ rp, const int* __restrict__ deg,
    const float* __restrict__ inv, uint4* __restrict__ agg1b) {
    int t = threadIdx.x;
    int lane = t & 63;
    int chain = lane >> 3, f = lane & 7;
    int node = blockIdx.x * 4 + (t >> 6);
    int len = deg[node];
    const int* cp = csr + rp[node];
    f32x2 c0 = {0, 0}, c1 = {0, 0}, c2 = {0, 0}, c3 = {0, 0};
    int j = chain;
    int s = (j < len) ? cp[j] : 0;
    while (j < len) {
        int jn = j + 8;
        int sn = (jn < len) ? cp[jn] : 0;
        uint2 u = xb8[s * 8 + f];
        c0 += cvt2_lo(u.x); c1 += cvt2_hi(u.x);
        c2 += cvt2_lo(u.y); c3 += cvt2_hi(u.y);
        j = jn; s = sn;
    }
    float a[8] = {c0[0], c0[1], c1[0], c1[1], c2[0], c2[1], c3[0], c3[1]};
#pragma unroll
    for (int k = 0; k < 8; k++) {
        a[k] += __shfl_xor(a[k], 8);
        a[k] += __shfl_xor(a[k], 16);
        a[k] += __shfl_xor(a[k], 32);
    }
    if (lane < 8) {
        float ic = inv[node];
        uint4 o;
        o.x = (unsigned)f2bf(a[0] * ic) | ((unsigned)f2bf(a[1] * ic) << 16);
        o.y = (unsigned)f2bf(a[2] * ic) | ((unsigned)f2bf(a[3] * ic) << 16);
        o.z = (unsigned)f2bf(a[4] * ic) | ((unsigned)f2bf(a[5] * ic) << 16);
        o.w = (unsigned)f2bf(a[6] * ic) | ((unsigned)f2bf(a[7] * ic) << 16);
        agg1b[node * 8 + f] = o;
    }
}

// ---------------- gather layer 2 (fp8, permuted cols) + BN fold ----------------
// 1 node/wave; 8 edge-chains x 8 lanes x 16B; packed f32x2 accumulate; index prefetch
__global__ __launch_bounds__(256) void k_agg2(
    const uint4* __restrict__ h1f8, const int* __restrict__ csr,
    const int* __restrict__ rp, const int* __restrict__ deg,
    const float* __restrict__ inv, const float* __restrict__ has,
    const float* __restrict__ statsp, uint4* __restrict__ a2b) {
    int t = threadIdx.x;
    int lane = t & 63;
    int chain = lane >> 3, f = lane & 7;
    int node = blockIdx.x * 4 + (t >> 6);
    int len = deg[node];
    const int* cp = csr + rp[node];
    f32x2 c[8];
#pragma unroll
    for (int k = 0; k < 8; k++) c[k] = (f32x2){0.f, 0.f};
    int j = chain;
    int s = (j < len) ? cp[j] : 0;
    while (j < len) {
        int jn = j + 8;
        int sn = (jn < len) ? cp[jn] : 0;
        uint4 u = h1f8[s * 8 + f];
        c[0] += cvt2_lo(u.x); c[1] += cvt2_hi(u.x);
        c[2] += cvt2_lo(u.y); c[3] += cvt2_hi(u.y);
        c[4] += cvt2_lo(u.z); c[5] += cvt2_hi(u.z);
        c[6] += cvt2_lo(u.w); c[7] += cvt2_hi(u.w);
        j = jn; s = sn;
    }
    float a[16];
#pragma unroll
    for (int k = 0; k < 8; k++) { a[2 * k] = c[k][0]; a[2 * k + 1] = c[k][1]; }
#pragma unroll
    for (int k = 0; k < 16; k++) {
        a[k] += __shfl_xor(a[k], 8);
        a[k] += __shfl_xor(a[k], 16);
        a[k] += __shfl_xor(a[k], 32);
    }
    if (lane < 8) {
        float ic = inv[node], hv = has[node];
        const float4* sc4 = (const float4*)statsp;
        const float4* sh4 = (const float4*)(statsp + 128);
        float v[16];
#pragma unroll
        for (int q = 0; q < 4; q++) {
            float4 sc = sc4[f * 4 + q];
            float4 sh = sh4[f * 4 + q];
            v[q * 4 + 0] = a[q * 4 + 0] * ic * sc.x + sh.x * hv;
            v[q * 4 + 1] = a[q * 4 + 1] * ic * sc.y + sh.y * hv;
            v[q * 4 + 2] = a[q * 4 + 2] * ic * sc.z + sh.z * hv;
            v[q * 4 + 3] = a[q * 4 + 3] * ic * sc.w + sh.w * hv;
        }
        uint4 o0, o1;
        o0.x = (unsigned)f2bf(v[0]) | ((unsigned)f2bf(v[1]) << 16);
        o0.y = (unsigned)f2bf(v[2]) | ((unsigned)f2bf(v[3]) << 16);
        o0.z = (unsigned)f2bf(v[4]) | ((unsigned)f2bf(v[5]) << 16);
        o0.w = (unsigned)f2bf(v[6]) | ((unsigned)f2bf(v[7]) << 16);
        o1.x = (unsigned)f2bf(v[8]) | ((unsigned)f2bf(v[9]) << 16);
        o1.y = (unsigned)f2bf(v[10]) | ((unsigned)f2bf(v[11]) << 16);
        o1.z = (unsigned)f2bf(v[12]) | ((unsigned)f2bf(v[13]) << 16);
        o1.w = (unsigned)f2bf(v[14]) | ((unsigned)f2bf(v[15]) << 16);
        a2b[node * 16 + f * 2] = o0;
        a2b[node * 16 + f * 2 + 1] = o1;
    }
}

// ---------------- layer 1 MFMA: C=[agg1|x]@[w1l;w1r]+b1l; L2norm; relu; BN stats ----
__global__ __launch_bounds__(256, 3) void k_gemm1(
    const uint4* __restrict__ agg1b, const uint4* __restrict__ xb,
    const uint4* __restrict__ W1T, const float* __restrict__ b1l,
    uint4* __restrict__ h1b, uint2* __restrict__ h1f8, float* __restrict__ part) {
    __shared__ unsigned short Wsm[128 * LDA];  // 34816 B
    __shared__ unsigned short Asm[64 * LDA];   // 17408 B
    __shared__ float cs[128], cq[128];
    const int t = threadIdx.x;
    const int w = t >> 6, lane = t & 63, quad = lane >> 4, l15 = lane & 15;
    if (t < 128) { cs[t] = 0.f; cq[t] = 0.f; }
    // stage W1T once (row=256B=16 uint4)
    {
        int r = t >> 1, h = t & 1;
#pragma unroll
        for (int i = 0; i < 8; i++) {
            uint4 v = W1T[r * 16 + h * 8 + i];
            *(uint4*)&Wsm[r * LDA + h * 64 + i * 8] = v;
        }
    }
    float bias[8];
#pragma unroll
    for (int nt = 0; nt < 8; nt++) bias[nt] = b1l[nt * 16 + l15];
    float colsum[8] = {0, 0, 0, 0, 0, 0, 0, 0};
    float colsq[8]  = {0, 0, 0, 0, 0, 0, 0, 0};

    for (int g = blockIdx.x; g < NT1; g += gridDim.x) {
        const int base = g * 64;
        const int valid = (NN - base < 64) ? (NN - base) : 64;
        __syncthreads();  // prev readback / W staging done
        {   // stage A: row m = [agg1b row m (128B) | xb row m (128B)]
            int m = t >> 2, p = t & 3;
            bool ok = m < valid;
            int gm = base + m;
            const uint4* src = (p < 2) ? agg1b : xb;
            int pc = p & 1;
#pragma unroll
            for (int i = 0; i < 4; i++) {
                uint4 v = ok ? src[gm * 8 + pc * 4 + i] : make_uint4(0, 0, 0, 0);
                *(uint4*)&Asm[m * LDA + p * 32 + i * 8] = v;
            }
        }
        __syncthreads();
        f32x4 acc[8];
#pragma unroll
        for (int nt = 0; nt < 8; nt++) acc[nt] = (f32x4){bias[nt], bias[nt], bias[nt], bias[nt]};
#pragma unroll
        for (int kc = 0; kc < 4; kc++) {
            s16x8 af = *(const s16x8*)&Asm[(16 * w + l15) * LDA + kc * 32 + quad * 8];
#pragma unroll
            for (int nt = 0; nt < 8; nt++) {
                s16x8 bf = *(const s16x8*)&Wsm[(nt * 16 + l15) * LDA + kc * 32 + quad * 8];
                acc[nt] = __builtin_amdgcn_mfma_f32_16x16x32_bf16(af, bf, acc[nt], 0, 0, 0);
            }
        }
        // epilogue: norm+relu+stats; bf16 into Asm; fp8 packed DIRECTLY (permuted cols)
        float ssr[4] = {0, 0, 0, 0};
#pragma unroll
        for (int nt = 0; nt < 8; nt++)
#pragma unroll
            for (int r = 0; r < 4; r++) ssr[r] += acc[nt][r] * acc[nt][r];
#pragma unroll
        for (int r = 0; r < 4; r++) {
            ssr[r] += __shfl_xor(ssr[r], 1); ssr[r] += __shfl_xor(ssr[r], 2);
            ssr[r] += __shfl_xor(ssr[r], 4); ssr[r] += __shfl_xor(ssr[r], 8);
        }
#pragma unroll
        for (int r = 0; r < 4; r++) {
            int mrow = 16 * w + quad * 4 + r;
            float iv = 1.0f / fmaxf(sqrtf(ssr[r]), 1e-12f);
            bool okr = mrow < valid;
            float v[8];
#pragma unroll
            for (int nt = 0; nt < 8; nt++) {
                float vv = fmaxf(acc[nt][r] * iv, 0.f);
                if (!okr) vv = 0.f;
                v[nt] = vv;
                colsum[nt] += vv;
                colsq[nt] += vv * vv;
                Asm[mrow * LDA + nt * 16 + l15] = f2bf(vv);
            }
            if (okr) {
                uint2 o;
                o.x = pk_fp8x4(v[0], v[1], v[2], v[3]);
                o.y = pk_fp8x4(v[4], v[5], v[6], v[7]);
                h1f8[(base + mrow) * 16 + l15] = o;   // permuted col' = l15*8+nt
            }
        }
        __syncthreads();
        {   // coalesced h1b store (row=256B=16 uint4)
            int m = t >> 2, p = t & 3;
            if (m < valid) {
                int gm = base + m;
#pragma unroll
                for (int i = 0; i < 4; i++) {
                    uint4 v = *(const uint4*)&Asm[m * LDA + p * 32 + i * 8];
                    h1b[gm * 16 + p * 4 + i] = v;
                }
            }
        }
    }
    __syncthreads();
#pragma unroll
    for (int nt = 0; nt < 8; nt++) {
        atomicAdd(&cs[nt * 16 + l15], colsum[nt]);
        atomicAdd(&cq[nt * 16 + l15], colsq[nt]);
    }
    __syncthreads();
    if (t < 128) {
        part[blockIdx.x * 256 + t] = cs[t];
        part[blockIdx.x * 256 + 128 + t] = cq[t];
    }
}

// ---------------- BN finalize: stats + permuted copy ----------------
__global__ void k_bnfin(const float* __restrict__ part, const float* __restrict__ gamma,
                        const float* __restrict__ beta, float* __restrict__ stats) {
    int t = threadIdx.x;  // 128 (channel)
    float s = 0.f, q = 0.f;
    for (int b = 0; b < PART_BLOCKS; b++) {
        s += part[b * 256 + t];
        q += part[b * 256 + 128 + t];
    }
    float mean = s / (float)NN;
    float var = q / (float)NN - mean * mean;
    float sc = gamma[t] * rsqrtf(var + 1e-5f);
    float sh = beta[t] - mean * sc;
    stats[t] = sc;
    stats[128 + t] = sh;
    int cp = (t & 15) * 8 + (t >> 4);   // permuted position of channel t
    stats[256 + cp] = sc;
    stats[384 + cp] = sh;
}

// ---------------- layer 2 MFMA (K=256) + L2norm + FC ----------------
__global__ __launch_bounds__(256, 3) void k_gemm2(
    const uint4* __restrict__ a2b, const uint4* __restrict__ h1b,
    const float* __restrict__ stats,
    const uint4* __restrict__ W2T, const float* __restrict__ b2l,
    const uint4* __restrict__ wfcT, const float* __restrict__ bfc,
    float* __restrict__ out) {
    __shared__ unsigned short Wsm[128 * LDA];
    __shared__ unsigned short Asm[64 * LDA];
    const int t = threadIdx.x;
    const int w = t >> 6, lane = t & 63, quad = lane >> 4, l15 = lane & 15;
    const int base = blockIdx.x * 64;
    const int valid = (NN - base < 64) ? (NN - base) : 64;

    f32x4 acc[8];
#pragma unroll
    for (int nt = 0; nt < 8; nt++) {
        float b = b2l[nt * 16 + l15];
        acc[nt] = (f32x4){b, b, b, b};
    }

#pragma unroll
    for (int phase = 0; phase < 2; phase++) {
        if (phase) __syncthreads();  // prev MFMA reads done
        {   // stage W half (W2T row = 512B = 32 uint4)
            int r = t >> 1, h = t & 1;
#pragma unroll
            for (int i = 0; i < 8; i++) {
                uint4 v = W2T[r * 32 + phase * 16 + h * 8 + i];
                *(uint4*)&Wsm[r * LDA + h * 64 + i * 8] = v;
            }
        }
        {   // stage A half
            int m = t >> 2, p = t & 3;
            bool ok = m < valid;
            int gm = base + m;
            if (phase == 0) {
#pragma unroll
                for (int i = 0; i < 4; i++) {
                    uint4 v = ok ? a2b[gm * 16 + p * 4 + i] : make_uint4(0, 0, 0, 0);
                    *(uint4*)&Asm[m * LDA + p * 32 + i * 8] = v;
                }
            } else {
                const float4* sc4 = (const float4*)stats;
                const float4* sh4 = (const float4*)(stats + 128);
#pragma unroll
                for (int i = 0; i < 4; i++) {
                    uint4 v = make_uint4(0, 0, 0, 0);
                    if (ok) {
                        v = h1b[gm * 16 + p * 4 + i];
                        int c4 = (p * 32 + i * 8) >> 2;
                        float4 s0 = sc4[c4], s1 = sc4[c4 + 1];
                        float4 t0 = sh4[c4], t1 = sh4[c4 + 1];
                        float e0 = bfl(v.x) * s0.x + t0.x, e1 = bfh(v.x) * s0.y + t0.y;
                        float e2 = bfl(v.y) * s0.z + t0.z, e3 = bfh(v.y) * s0.w + t0.w;
                        float e4 = bfl(v.z) * s1.x + t1.x, e5 = bfh(v.z) * s1.y + t1.y;
                        float e6 = bfl(v.w) * s1.z + t1.z, e7 = bfh(v.w) * s1.w + t1.w;
                        v.x = (unsigned)f2bf(e0) | ((unsigned)f2bf(e1) << 16);
                        v.y = (unsigned)f2bf(e2) | ((unsigned)f2bf(e3) << 16);
                        v.z = (unsigned)f2bf(e4) | ((unsigned)f2bf(e5) << 16);
                        v.w = (unsigned)f2bf(e6) | ((unsigned)f2bf(e7) << 16);
                    }
                    *(uint4*)&Asm[m * LDA + p * 32 + i * 8] = v;
                }
            }
        }
        __syncthreads();
#pragma unroll
        for (int kc = 0; kc < 4; kc++) {
            s16x8 af = *(const s16x8*)&Asm[(16 * w + l15) * LDA + kc * 32 + quad * 8];
#pragma unroll
            for (int nt = 0; nt < 8; nt++) {
                s16x8 bf = *(const s16x8*)&Wsm[(nt * 16 + l15) * LDA + kc * 32 + quad * 8];
                acc[nt] = __builtin_amdgcn_mfma_f32_16x16x32_bf16(af, bf, acc[nt], 0, 0, 0);
            }
        }
    }
    // epilogue: L2 norm (no relu), h2 -> Asm (own rows)
    float ssr[4] = {0, 0, 0, 0};
#pragma unroll
    for (int nt = 0; nt < 8; nt++)
#pragma unroll
        for (int r = 0; r < 4; r++) ssr[r] += acc[nt][r] * acc[nt][r];
#pragma unroll
    for (int r = 0; r < 4; r++) {
        ssr[r] += __shfl_xor(ssr[r], 1); ssr[r] += __shfl_xor(ssr[r], 2);
        ssr[r] += __shfl_xor(ssr[r], 4); ssr[r] += __shfl_xor(ssr[r], 8);
    }
#pragma unroll
    for (int r = 0; r < 4; r++) {
        int mrow = 16 * w + quad * 4 + r;
        float iv = 1.0f / fmaxf(sqrtf(ssr[r]), 1e-12f);
#pragma unroll
        for (int nt = 0; nt < 8; nt++) {
            Asm[mrow * LDA + nt * 16 + l15] = f2bf(acc[nt][r] * iv);
        }
    }
    __syncthreads();  // h2 writes + all W reads done
    // stage wfcT (16 rows x 256B = 16 uint4/row)
    if (t < 64) {
        int n = t >> 2, p = t & 3;
#pragma unroll
        for (int i = 0; i < 4; i++) {
            uint4 v = wfcT[n * 16 + p * 4 + i];
            *(uint4*)&Wsm[n * LDA + p * 32 + i * 8] = v;
        }
    }
    __syncthreads();
    // FC: 16x16 tile per wave, K=128
    f32x4 a2;
    {
        float b = bfc[l15];
        a2 = (f32x4){b, b, b, b};
    }
#pragma unroll
    for (int kc = 0; kc < 4; kc++) {
        s16x8 af = *(const s16x8*)&Asm[(16 * w + l15) * LDA + kc * 32 + quad * 8];
        s16x8 bf = *(const s16x8*)&Wsm[l15 * LDA + kc * 32 + quad * 8];
        a2 = __builtin_amdgcn_mfma_f32_16x16x32_bf16(af, bf, a2, 0, 0, 0);
    }
#pragma unroll
    for (int r = 0; r < 4; r++) {
        int mrow = 16 * w + quad * 4 + r;
        if (mrow < valid) out[(base + mrow) * 16 + l15] = a2[r];
    }
}

extern "C" void kernel_launch(void* const* d_in, const int* in_sizes, int n_in,
                              void* d_out, int out_size, void* d_ws, size_t ws_size,
                              hipStream_t stream) {
    const float* x     = (const float*)d_in[0];
    const int*   ei    = (const int*)d_in[1];
    const float* w1l   = (const float*)d_in[2];
    const float* b1l   = (const float*)d_in[3];
    const float* w1r   = (const float*)d_in[4];
    const float* gamma = (const float*)d_in[5];
    const float* beta  = (const float*)d_in[6];
    const float* w2l   = (const float*)d_in[7];
    const float* b2l   = (const float*)d_in[8];
    const float* w2r   = (const float*)d_in[9];
    const float* wfc   = (const float*)d_in[10];
    const float* bfc   = (const float*)d_in[11];
    float* out = (float*)d_out;

    float* W = (float*)d_ws;
    int* deg8  = (int*)(W + OFS_DEG8);
    int* deg   = (int*)(W + OFS_DEG);
    int* rp    = (int*)(W + OFS_RP);
    int* bsum  = (int*)(W + OFS_BSUM);
    unsigned short* rank = (unsigned short*)(W + OFS_RANK);
    int* csr   = (int*)(W + OFS_CSR);
    float* inv   = W + OFS_INV;
    float* has   = W + OFS_HAS;
    unsigned* xb   = (unsigned*)(W + OFS_XB);
    unsigned* xb8  = (unsigned*)(W + OFS_XB8);
    unsigned* a1b  = (unsigned*)(W + OFS_A1B);
    unsigned* h1b  = (unsigned*)(W + OFS_H1B);
    unsigned* h1f8 = (unsigned*)(W + OFS_H1F8);
    unsigned* a2b  = (unsigned*)(W + OFS_A2B);
    unsigned short* W1T  = (unsigned short*)(W + OFS_W1T);
    unsigned short* W2T  = (unsigned short*)(W + OFS_W2T);
    unsigned short* wfcT = (unsigned short*)(W + OFS_WFCT);
    float* stats = W + OFS_STATS;          // [sc|sh|sc'|sh'] (512)
    float* part  = W + OFS_PART;

    hipMemsetAsync(deg8, 0, 8 * NN * sizeof(int), stream);

    k_init<<<CAST_BLOCKS + PREP_BLOCKS, 256, 0, stream>>>(
        (const float4*)x, (uint2*)xb, xb8, w1l, w1r, w2l, w2r, wfc, W1T, W2T, wfcT);
    k_rank <<<NE / 256, 256, 0, stream>>>(ei, deg8, rank);
    k_scan1<<<NB1, 256, 0, stream>>>(deg8, deg, bsum);
    k_scan3<<<NB1, 256, 0, stream>>>(deg, bsum, rp, deg8, inv, has);
    k_fill <<<NE / 256, 256, 0, stream>>>(ei, rank, deg8, csr);

    k_agg1 <<<NN / 4, 256, 0, stream>>>((const uint2*)xb8, csr, rp, deg, inv, (uint4*)a1b);
    k_gemm1<<<PART_BLOCKS, 256, 0, stream>>>((const uint4*)a1b, (const uint4*)xb,
                                             (const uint4*)W1T, b1l, (uint4*)h1b,
                                             (uint2*)h1f8, part);
    k_bnfin<<<1, 128, 0, stream>>>(part, gamma, beta, stats);
    k_agg2 <<<NN / 4, 256, 0, stream>>>((const uint4*)h1f8, csr, rp, deg, inv, has,
                                        stats + 256, (uint4*)a2b);
    k_gemm2<<<NT1, 256, 0, stream>>>((const uint4*)a2b, (const uint4*)h1b, stats,
                                     (const uint4*)W2T, b2l, (const uint4*)wfcT, bfc, out);
}

// Round 9
// 397.182 us; speedup vs baseline: 1.9531x; 1.0600x over previous
//
#include <hip/hip_runtime.h>
#include <math.h>

#define NN 100000
#define NE 1600000
#define NB1 391           // ceil(NN/256) scan blocks
#define PART_BLOCKS 768
#define NT1 1563          // ceil(NN/64) M-tiles
#define LDA 136           // padded LDS row stride (ushorts): 272 B, 16B-aligned

typedef float f32x4 __attribute__((ext_vector_type(4)));
typedef float f32x2 __attribute__((ext_vector_type(2)));
typedef short s16x8 __attribute__((ext_vector_type(8)));

// ---- ws layout (4-byte words) ----
#define OFS_DEG8  0                     // int[8][NN] sharded histogram -> base8 after scan3
#define OFS_DEG   (8*NN)                // int[NN]
#define OFS_RP    (9*NN)                // int[NN]
#define OFS_BSUM  (10*NN)
#define OFS_RANK  (10*NN + 1024)        // ushort[NE] -> NE/2 words
#define OFS_CSR   (OFS_RANK + NE/2)
#define OFS_INV   (OFS_CSR + NE)
#define OFS_HAS   (OFS_INV + NN)
#define OFS_XB    (OFS_HAS + NN)        // x bf16 [NN][64]   -> 32*NN words
#define OFS_XB8   (OFS_XB + 32*NN)      // x fp8 [NN][64]    -> 16*NN words
#define OFS_A1B   (OFS_XB8 + 16*NN)     // agg1 bf16 [NN][64]-> 32*NN
#define OFS_H1B   (OFS_A1B + 32*NN)     // h1 bf16 [NN][128] -> 64*NN
#define OFS_H1F8  (OFS_H1B + 64*NN)     // h1 fp8 PERMUTED [NN][128] -> 32*NN
#define OFS_A2B   (OFS_H1F8 + 32*NN)    // BN'd agg2 bf16 PERMUTED [NN][128] -> 64*NN
#define OFS_W1T   (OFS_A2B + 64*NN)     // [128][128] ush -> 8192 words
#define OFS_W2T   (OFS_W1T + 8192)      // [128][256] ush (lin_l K-rows permuted) -> 16384
#define OFS_WFCT  (OFS_W2T + 16384)     // [16][128] ush -> 1024 words
#define OFS_STATS (OFS_WFCT + 1024)     // 512: [sc 128][sh 128][sc' 128][sh' 128]
#define OFS_PART  (OFS_STATS + 512)     // 768*256

// col permutation: c' = l15*8 + nt  <->  c = nt*16 + l15  (P(c') = (c'&7)*16 + (c'>>3))

__device__ __forceinline__ unsigned short f2bf(float f) {
    unsigned u = __float_as_uint(f);
    return (unsigned short)((u + 0x7FFFu + ((u >> 16) & 1u)) >> 16);
}
__device__ __forceinline__ float bfl(unsigned u) { return __uint_as_float(u << 16); }
__device__ __forceinline__ float bfh(unsigned u) { return __uint_as_float(u & 0xFFFF0000u); }

// ---- fp8 e4m3 pack/unpack (HW cvt on gfx950; software fallback) ----
#if __has_builtin(__builtin_amdgcn_cvt_pk_f32_fp8) && __has_builtin(__builtin_amdgcn_cvt_pk_fp8_f32)
__device__ __forceinline__ f32x2 cvt2_lo(unsigned w) {
    return __builtin_amdgcn_cvt_pk_f32_fp8((int)w, false);
}
__device__ __forceinline__ f32x2 cvt2_hi(unsigned w) {
    return __builtin_amdgcn_cvt_pk_f32_fp8((int)w, true);
}
__device__ __forceinline__ unsigned pk_fp8x4(float a, float b, float c, float d) {
    int w = __builtin_amdgcn_cvt_pk_fp8_f32(a, b, 0, false);
    w = __builtin_amdgcn_cvt_pk_fp8_f32(c, d, w, true);
    return (unsigned)w;
}
#else
__device__ __forceinline__ float sw_fp82f(unsigned v) {
    unsigned s = (v & 0x80u) << 24;
    unsigned e = (v >> 3) & 15u, m = v & 7u;
    float r = (e == 0) ? ((float)m * 0.001953125f)
                       : __uint_as_float(((e + 120u) << 23) | (m << 20));
    return __uint_as_float(s | __float_as_uint(r));
}
__device__ __forceinline__ f32x2 cvt2_lo(unsigned w) {
    return (f32x2){sw_fp82f(w & 255u), sw_fp82f((w >> 8) & 255u)};
}
__device__ __forceinline__ f32x2 cvt2_hi(unsigned w) {
    return (f32x2){sw_fp82f((w >> 16) & 255u), sw_fp82f(w >> 24)};
}
__device__ __forceinline__ unsigned sw_f2fp8(float f) {
    unsigned b = __float_as_uint(f);
    unsigned s = (b >> 24) & 0x80u;
    float af = fabsf(f);
    if (af < 0.0009765625f) return s;
    if (af >= 448.f) return s | 0x7Eu;
    int e = (int)((b >> 23) & 255u) - 127;
    if (e < -6) {
        int q = (int)rintf(af * 512.f);
        return s | (unsigned)q;
    }
    unsigned man = b & 0x7FFFFFu;
    unsigned r = (man + 0x7FFFFu + ((man >> 20) & 1u)) >> 20;
    unsigned enc = ((unsigned)(e + 7) << 3) + r;
    if (enc >= 0x7Fu) enc = 0x7Eu;
    return s | enc;
}
__device__ __forceinline__ unsigned pk_fp8x4(float a, float b, float c, float d) {
    return sw_f2fp8(a) | (sw_f2fp8(b) << 8) | (sw_f2fp8(c) << 16) | (sw_f2fp8(d) << 24);
}
#endif

// ---------------- init: cast x -> bf16+fp8, weights -> transposed bf16 ----------------
#define CAST_BLOCKS 6250   // NN*16/256
#define PREP_BLOCKS 200    // (16384+32768+2048)/256
__global__ void k_init(const float4* __restrict__ x4, uint2* __restrict__ xb,
                       unsigned* __restrict__ xb8,
                       const float* __restrict__ w1l, const float* __restrict__ w1r,
                       const float* __restrict__ w2l, const float* __restrict__ w2r,
                       const float* __restrict__ wfc,
                       unsigned short* __restrict__ W1T, unsigned short* __restrict__ W2T,
                       unsigned short* __restrict__ wfcT) {
    int b = blockIdx.x, t = threadIdx.x;
    if (b < CAST_BLOCKS) {
        int i = b * 256 + t;
        float4 v = x4[i];
        uint2 o;
        o.x = (unsigned)f2bf(v.x) | ((unsigned)f2bf(v.y) << 16);
        o.y = (unsigned)f2bf(v.z) | ((unsigned)f2bf(v.w) << 16);
        xb[i] = o;
        xb8[i] = pk_fp8x4(v.x, v.y, v.z, v.w);
        return;
    }
    int u = (b - CAST_BLOCKS) * 256 + t;
    if (u < 16384) {
        int n = u >> 7, k = u & 127;
        float v = (k < 64) ? w1l[k * 128 + n] : w1r[(k - 64) * 128 + n];
        W1T[u] = f2bf(v);
    } else if (u < 16384 + 32768) {
        int u2 = u - 16384;
        int n = u2 >> 8, kk = u2 & 255;
        float v;
        if (kk < 128) {
            int pk = (kk & 7) * 16 + (kk >> 3);   // permuted lin_l K-row
            v = w2l[pk * 128 + n];
        } else {
            v = w2r[(kk - 128) * 128 + n];
        }
        W2T[u2] = f2bf(v);
    } else {
        int u3 = u - 16384 - 32768;
        int o = u3 >> 7, k = u3 & 127;
        wfcT[u3] = f2bf(wfc[k * 16 + o]);
    }
}

// ---------------- CSR build: sharded rank histogram ----------------
__global__ void k_rank(const int* __restrict__ ei, int* __restrict__ deg8,
                       unsigned short* __restrict__ rank) {
    int e = blockIdx.x * 256 + threadIdx.x;
    int c = blockIdx.x & 7;
    int d = ei[NE + e];
    int r = atomicAdd(&deg8[c * NN + d], 1);
    rank[e] = (unsigned short)r;
}

__global__ void k_scan1(const int* __restrict__ deg8, int* __restrict__ deg,
                        int* __restrict__ bsum) {
    __shared__ int sb[256];
    int t = threadIdx.x;
    int i = blockIdx.x * 256 + t;
    int s = 0;
    if (i < NN) {
#pragma unroll
        for (int c = 0; c < 8; c++) s += deg8[c * NN + i];
        deg[i] = s;
    }
    sb[t] = s;
    __syncthreads();
    for (int off = 128; off > 0; off >>= 1) {
        if (t < off) sb[t] += sb[t + off];
        __syncthreads();
    }
    if (t == 0) bsum[blockIdx.x] = sb[0];
}

// per-node start offsets (self-computes block prefix of bsum); deg8 -> base8 in place
__global__ void k_scan3(const int* __restrict__ deg, const int* __restrict__ bsum,
                        int* __restrict__ rp, int* __restrict__ base8,
                        float* __restrict__ inv, float* __restrict__ has) {
    __shared__ int sb[256];
    __shared__ int sbase;
    int t = threadIdx.x;
    // redundant per-block exclusive prefix over bsum
    int partial = 0;
    for (int b = t; b < blockIdx.x; b += 256) partial += bsum[b];
    sb[t] = partial;
    __syncthreads();
    for (int off = 128; off > 0; off >>= 1) {
        if (t < off) sb[t] += sb[t + off];
        __syncthreads();
    }
    if (t == 0) sbase = sb[0];
    __syncthreads();
    int blkbase = sbase;
    __syncthreads();
    int i = blockIdx.x * 256 + t;
    int d = (i < NN) ? deg[i] : 0;
    sb[t] = d;
    __syncthreads();
    for (int off = 1; off < 256; off <<= 1) {
        int u = (t >= off) ? sb[t - off] : 0;
        __syncthreads();
        sb[t] += u;
        __syncthreads();
    }
    if (i < NN) {
        int start = sb[t] - d + blkbase;
        rp[i] = start;
        inv[i] = 1.0f / fmaxf((float)d, 1.0f);
        has[i] = (d > 0) ? 1.0f : 0.0f;
        int run = start;
#pragma unroll
        for (int c = 0; c < 8; c++) {
            int dc = base8[c * NN + i];
            base8[c * NN + i] = run;
            run += dc;
        }
    }
}

__global__ void k_fill(const int* __restrict__ ei, const unsigned short* __restrict__ rank,
                       const int* __restrict__ base8, int* __restrict__ csr) {
    int e = blockIdx.x * 256 + threadIdx.x;
    int c = blockIdx.x & 7;
    int d = ei[NE + e];
    int s = ei[e];
    int pos = base8[c * NN + d] + (int)rank[e];
    __builtin_nontemporal_store(s, &csr[pos]);
}

// ---------------- gather layer 1 (fp8): agg1b[n] = bf16(mean x[s]) ----------------
// 8 nodes/wave, 8 lanes/node (lane f owns cols f*8..f*8+7); no shuffles; divergent loop
__global__ __launch_bounds__(256) void k_agg1(
    const uint2* __restrict__ xb8, const int* __restrict__ csr,
    const int* __restrict__ rp, const int* __restrict__ deg,
    const float* __restrict__ inv, uint4* __restrict__ agg1b) {
    int t = threadIdx.x;
    int lane = t & 63;
    int grp = lane >> 3, f = lane & 7;
    int node = blockIdx.x * 32 + (t >> 6) * 8 + grp;
    int len = deg[node];
    const int* cp = csr + rp[node];
    f32x2 c0 = {0, 0}, c1 = {0, 0}, c2 = {0, 0}, c3 = {0, 0};
    int j = 0;
    int s = (0 < len) ? cp[0] : 0;
    while (j < len) {
        int jn = j + 1;
        int sn = (jn < len) ? cp[jn] : 0;
        uint2 u = xb8[s * 8 + f];
        c0 += cvt2_lo(u.x); c1 += cvt2_hi(u.x);
        c2 += cvt2_lo(u.y); c3 += cvt2_hi(u.y);
        j = jn; s = sn;
    }
    float ic = inv[node];
    uint4 o;
    o.x = (unsigned)f2bf(c0[0] * ic) | ((unsigned)f2bf(c0[1] * ic) << 16);
    o.y = (unsigned)f2bf(c1[0] * ic) | ((unsigned)f2bf(c1[1] * ic) << 16);
    o.z = (unsigned)f2bf(c2[0] * ic) | ((unsigned)f2bf(c2[1] * ic) << 16);
    o.w = (unsigned)f2bf(c3[0] * ic) | ((unsigned)f2bf(c3[1] * ic) << 16);
    agg1b[node * 8 + f] = o;
}

// ---------------- gather layer 2 (fp8, permuted cols) + BN fold ----------------
// 8 nodes/wave, 8 lanes/node (lane f owns permuted cols f*16..f*16+15); no shuffles
__global__ __launch_bounds__(256) void k_agg2(
    const uint4* __restrict__ h1f8, const int* __restrict__ csr,
    const int* __restrict__ rp, const int* __restrict__ deg,
    const float* __restrict__ inv, const float* __restrict__ has,
    const float* __restrict__ statsp, uint4* __restrict__ a2b) {
    int t = threadIdx.x;
    int lane = t & 63;
    int grp = lane >> 3, f = lane & 7;
    int node = blockIdx.x * 32 + (t >> 6) * 8 + grp;
    int len = deg[node];
    const int* cp = csr + rp[node];
    f32x2 c[8];
#pragma unroll
    for (int k = 0; k < 8; k++) c[k] = (f32x2){0.f, 0.f};
    int j = 0;
    int s = (0 < len) ? cp[0] : 0;
    while (j < len) {
        int jn = j + 1;
        int sn = (jn < len) ? cp[jn] : 0;
        uint4 u = h1f8[s * 8 + f];
        c[0] += cvt2_lo(u.x); c[1] += cvt2_hi(u.x);
        c[2] += cvt2_lo(u.y); c[3] += cvt2_hi(u.y);
        c[4] += cvt2_lo(u.z); c[5] += cvt2_hi(u.z);
        c[6] += cvt2_lo(u.w); c[7] += cvt2_hi(u.w);
        j = jn; s = sn;
    }
    float ic = inv[node], hv = has[node];
    const float4* sc4 = (const float4*)statsp;
    const float4* sh4 = (const float4*)(statsp + 128);
    float v[16];
#pragma unroll
    for (int q = 0; q < 4; q++) {
        float4 sc = sc4[f * 4 + q];
        float4 sh = sh4[f * 4 + q];
        v[q * 4 + 0] = c[q * 2][0] * ic * sc.x + sh.x * hv;
        v[q * 4 + 1] = c[q * 2][1] * ic * sc.y + sh.y * hv;
        v[q * 4 + 2] = c[q * 2 + 1][0] * ic * sc.z + sh.z * hv;
        v[q * 4 + 3] = c[q * 2 + 1][1] * ic * sc.w + sh.w * hv;
    }
    uint4 o0, o1;
    o0.x = (unsigned)f2bf(v[0]) | ((unsigned)f2bf(v[1]) << 16);
    o0.y = (unsigned)f2bf(v[2]) | ((unsigned)f2bf(v[3]) << 16);
    o0.z = (unsigned)f2bf(v[4]) | ((unsigned)f2bf(v[5]) << 16);
    o0.w = (unsigned)f2bf(v[6]) | ((unsigned)f2bf(v[7]) << 16);
    o1.x = (unsigned)f2bf(v[8]) | ((unsigned)f2bf(v[9]) << 16);
    o1.y = (unsigned)f2bf(v[10]) | ((unsigned)f2bf(v[11]) << 16);
    o1.z = (unsigned)f2bf(v[12]) | ((unsigned)f2bf(v[13]) << 16);
    o1.w = (unsigned)f2bf(v[14]) | ((unsigned)f2bf(v[15]) << 16);
    a2b[node * 16 + f * 2] = o0;
    a2b[node * 16 + f * 2 + 1] = o1;
}

// ---------------- layer 1 MFMA: C=[agg1|x]@[w1l;w1r]+b1l; L2norm; relu; BN stats ----
__global__ __launch_bounds__(256, 3) void k_gemm1(
    const uint4* __restrict__ agg1b, const uint4* __restrict__ xb,
    const uint4* __restrict__ W1T, const float* __restrict__ b1l,
    uint4* __restrict__ h1b, uint2* __restrict__ h1f8, float* __restrict__ part) {
    __shared__ unsigned short Wsm[128 * LDA];  // 34816 B
    __shared__ unsigned short Asm[64 * LDA];   // 17408 B
    __shared__ float cs[128], cq[128];
    const int t = threadIdx.x;
    const int w = t >> 6, lane = t & 63, quad = lane >> 4, l15 = lane & 15;
    if (t < 128) { cs[t] = 0.f; cq[t] = 0.f; }
    // stage W1T once (row=256B=16 uint4)
    {
        int r = t >> 1, h = t & 1;
#pragma unroll
        for (int i = 0; i < 8; i++) {
            uint4 v = W1T[r * 16 + h * 8 + i];
            *(uint4*)&Wsm[r * LDA + h * 64 + i * 8] = v;
        }
    }
    float bias[8];
#pragma unroll
    for (int nt = 0; nt < 8; nt++) bias[nt] = b1l[nt * 16 + l15];
    float colsum[8] = {0, 0, 0, 0, 0, 0, 0, 0};
    float colsq[8]  = {0, 0, 0, 0, 0, 0, 0, 0};

    for (int g = blockIdx.x; g < NT1; g += gridDim.x) {
        const int base = g * 64;
        const int valid = (NN - base < 64) ? (NN - base) : 64;
        __syncthreads();  // prev readback / W staging done
        {   // stage A: row m = [agg1b row m (128B) | xb row m (128B)]
            int m = t >> 2, p = t & 3;
            bool ok = m < valid;
            int gm = base + m;
            const uint4* src = (p < 2) ? agg1b : xb;
            int pc = p & 1;
#pragma unroll
            for (int i = 0; i < 4; i++) {
                uint4 v = ok ? src[gm * 8 + pc * 4 + i] : make_uint4(0, 0, 0, 0);
                *(uint4*)&Asm[m * LDA + p * 32 + i * 8] = v;
            }
        }
        __syncthreads();
        f32x4 acc[8];
#pragma unroll
        for (int nt = 0; nt < 8; nt++) acc[nt] = (f32x4){bias[nt], bias[nt], bias[nt], bias[nt]};
#pragma unroll
        for (int kc = 0; kc < 4; kc++) {
            s16x8 af = *(const s16x8*)&Asm[(16 * w + l15) * LDA + kc * 32 + quad * 8];
#pragma unroll
            for (int nt = 0; nt < 8; nt++) {
                s16x8 bf = *(const s16x8*)&Wsm[(nt * 16 + l15) * LDA + kc * 32 + quad * 8];
                acc[nt] = __builtin_amdgcn_mfma_f32_16x16x32_bf16(af, bf, acc[nt], 0, 0, 0);
            }
        }
        // epilogue: norm+relu+stats; bf16 into Asm; fp8 packed DIRECTLY (permuted cols)
        float ssr[4] = {0, 0, 0, 0};
#pragma unroll
        for (int nt = 0; nt < 8; nt++)
#pragma unroll
            for (int r = 0; r < 4; r++) ssr[r] += acc[nt][r] * acc[nt][r];
#pragma unroll
        for (int r = 0; r < 4; r++) {
            ssr[r] += __shfl_xor(ssr[r], 1); ssr[r] += __shfl_xor(ssr[r], 2);
            ssr[r] += __shfl_xor(ssr[r], 4); ssr[r] += __shfl_xor(ssr[r], 8);
        }
#pragma unroll
        for (int r = 0; r < 4; r++) {
            int mrow = 16 * w + quad * 4 + r;
            float iv = 1.0f / fmaxf(sqrtf(ssr[r]), 1e-12f);
            bool okr = mrow < valid;
            float v[8];
#pragma unroll
            for (int nt = 0; nt < 8; nt++) {
                float vv = fmaxf(acc[nt][r] * iv, 0.f);
                if (!okr) vv = 0.f;
                v[nt] = vv;
                colsum[nt] += vv;
                colsq[nt] += vv * vv;
                Asm[mrow * LDA + nt * 16 + l15] = f2bf(vv);
            }
            if (okr) {
                uint2 o;
                o.x = pk_fp8x4(v[0], v[1], v[2], v[3]);
                o.y = pk_fp8x4(v[4], v[5], v[6], v[7]);
                h1f8[(base + mrow) * 16 + l15] = o;   // permuted col' = l15*8+nt
            }
        }
        __syncthreads();
        {   // coalesced h1b store (row=256B=16 uint4)
            int m = t >> 2, p = t & 3;
            if (m < valid) {
                int gm = base + m;
#pragma unroll
                for (int i = 0; i < 4; i++) {
                    uint4 v = *(const uint4*)&Asm[m * LDA + p * 32 + i * 8];
                    h1b[gm * 16 + p * 4 + i] = v;
                }
            }
        }
    }
    __syncthreads();
#pragma unroll
    for (int nt = 0; nt < 8; nt++) {
        atomicAdd(&cs[nt * 16 + l15], colsum[nt]);
        atomicAdd(&cq[nt * 16 + l15], colsq[nt]);
    }
    __syncthreads();
    if (t < 128) {
        part[blockIdx.x * 256 + t] = cs[t];
        part[blockIdx.x * 256 + 128 + t] = cq[t];
    }
}

// ---------------- BN finalize: stats + permuted copy ----------------
__global__ void k_bnfin(const float* __restrict__ part, const float* __restrict__ gamma,
                        const float* __restrict__ beta, float* __restrict__ stats) {
    int t = threadIdx.x;  // 128 (channel)
    float s = 0.f, q = 0.f;
    for (int b = 0; b < PART_BLOCKS; b++) {
        s += part[b * 256 + t];
        q += part[b * 256 + 128 + t];
    }
    float mean = s / (float)NN;
    float var = q / (float)NN - mean * mean;
    float sc = gamma[t] * rsqrtf(var + 1e-5f);
    float sh = beta[t] - mean * sc;
    stats[t] = sc;
    stats[128 + t] = sh;
    int cp = (t & 15) * 8 + (t >> 4);   // permuted position of channel t
    stats[256 + cp] = sc;
    stats[384 + cp] = sh;
}

// ---------------- layer 2 MFMA (K=256) + L2norm + FC ----------------
__global__ __launch_bounds__(256, 3) void k_gemm2(
    const uint4* __restrict__ a2b, const uint4* __restrict__ h1b,
    const float* __restrict__ stats,
    const uint4* __restrict__ W2T, const float* __restrict__ b2l,
    const uint4* __restrict__ wfcT, const float* __restrict__ bfc,
    float* __restrict__ out) {
    __shared__ unsigned short Wsm[128 * LDA];
    __shared__ unsigned short Asm[64 * LDA];
    const int t = threadIdx.x;
    const int w = t >> 6, lane = t & 63, quad = lane >> 4, l15 = lane & 15;
    const int base = blockIdx.x * 64;
    const int valid = (NN - base < 64) ? (NN - base) : 64;

    f32x4 acc[8];
#pragma unroll
    for (int nt = 0; nt < 8; nt++) {
        float b = b2l[nt * 16 + l15];
        acc[nt] = (f32x4){b, b, b, b};
    }

#pragma unroll
    for (int phase = 0; phase < 2; phase++) {
        if (phase) __syncthreads();  // prev MFMA reads done
        {   // stage W half (W2T row = 512B = 32 uint4)
            int r = t >> 1, h = t & 1;
#pragma unroll
            for (int i = 0; i < 8; i++) {
                uint4 v = W2T[r * 32 + phase * 16 + h * 8 + i];
                *(uint4*)&Wsm[r * LDA + h * 64 + i * 8] = v;
            }
        }
        {   // stage A half
            int m = t >> 2, p = t & 3;
            bool ok = m < valid;
            int gm = base + m;
            if (phase == 0) {
#pragma unroll
                for (int i = 0; i < 4; i++) {
                    uint4 v = ok ? a2b[gm * 16 + p * 4 + i] : make_uint4(0, 0, 0, 0);
                    *(uint4*)&Asm[m * LDA + p * 32 + i * 8] = v;
                }
            } else {
                const float4* sc4 = (const float4*)stats;
                const float4* sh4 = (const float4*)(stats + 128);
#pragma unroll
                for (int i = 0; i < 4; i++) {
                    uint4 v = make_uint4(0, 0, 0, 0);
                    if (ok) {
                        v = h1b[gm * 16 + p * 4 + i];
                        int c4 = (p * 32 + i * 8) >> 2;
                        float4 s0 = sc4[c4], s1 = sc4[c4 + 1];
                        float4 t0 = sh4[c4], t1 = sh4[c4 + 1];
                        float e0 = bfl(v.x) * s0.x + t0.x, e1 = bfh(v.x) * s0.y + t0.y;
                        float e2 = bfl(v.y) * s0.z + t0.z, e3 = bfh(v.y) * s0.w + t0.w;
                        float e4 = bfl(v.z) * s1.x + t1.x, e5 = bfh(v.z) * s1.y + t1.y;
                        float e6 = bfl(v.w) * s1.z + t1.z, e7 = bfh(v.w) * s1.w + t1.w;
                        v.x = (unsigned)f2bf(e0) | ((unsigned)f2bf(e1) << 16);
                        v.y = (unsigned)f2bf(e2) | ((unsigned)f2bf(e3) << 16);
                        v.z = (unsigned)f2bf(e4) | ((unsigned)f2bf(e5) << 16);
                        v.w = (unsigned)f2bf(e6) | ((unsigned)f2bf(e7) << 16);
                    }
                    *(uint4*)&Asm[m * LDA + p * 32 + i * 8] = v;
                }
            }
        }
        __syncthreads();
#pragma unroll
        for (int kc = 0; kc < 4; kc++) {
            s16x8 af = *(const s16x8*)&Asm[(16 * w + l15) * LDA + kc * 32 + quad * 8];
#pragma unroll
            for (int nt = 0; nt < 8; nt++) {
                s16x8 bf = *(const s16x8*)&Wsm[(nt * 16 + l15) * LDA + kc * 32 + quad * 8];
                acc[nt] = __builtin_amdgcn_mfma_f32_16x16x32_bf16(af, bf, acc[nt], 0, 0, 0);
            }
        }
    }
    // epilogue: L2 norm (no relu), h2 -> Asm (own rows)
    float ssr[4] = {0, 0, 0, 0};
#pragma unroll
    for (int nt = 0; nt < 8; nt++)
#pragma unroll
        for (int r = 0; r < 4; r++) ssr[r] += acc[nt][r] * acc[nt][r];
#pragma unroll
    for (int r = 0; r < 4; r++) {
        ssr[r] += __shfl_xor(ssr[r], 1); ssr[r] += __shfl_xor(ssr[r], 2);
        ssr[r] += __shfl_xor(ssr[r], 4); ssr[r] += __shfl_xor(ssr[r], 8);
    }
#pragma unroll
    for (int r = 0; r < 4; r++) {
        int mrow = 16 * w + quad * 4 + r;
        float iv = 1.0f / fmaxf(sqrtf(ssr[r]), 1e-12f);
#pragma unroll
        for (int nt = 0; nt < 8; nt++) {
            Asm[mrow * LDA + nt * 16 + l15] = f2bf(acc[nt][r] * iv);
        }
    }
    __syncthreads();  // h2 writes + all W reads done
    // stage wfcT (16 rows x 256B = 16 uint4/row)
    if (t < 64) {
        int n = t >> 2, p = t & 3;
#pragma unroll
        for (int i = 0; i < 4; i++) {
            uint4 v = wfcT[n * 16 + p * 4 + i];
            *(uint4*)&Wsm[n * LDA + p * 32 + i * 8] = v;
        }
    }
    __syncthreads();
    // FC: 16x16 tile per wave, K=128
    f32x4 a2;
    {
        float b = bfc[l15];
        a2 = (f32x4){b, b, b, b};
    }
#pragma unroll
    for (int kc = 0; kc < 4; kc++) {
        s16x8 af = *(const s16x8*)&Asm[(16 * w + l15) * LDA + kc * 32 + quad * 8];
        s16x8 bf = *(const s16x8*)&Wsm[l15 * LDA + kc * 32 + quad * 8];
        a2 = __builtin_amdgcn_mfma_f32_16x16x32_bf16(af, bf, a2, 0, 0, 0);
    }
#pragma unroll
    for (int r = 0; r < 4; r++) {
        int mrow = 16 * w + quad * 4 + r;
        if (mrow < valid) out[(base + mrow) * 16 + l15] = a2[r];
    }
}

extern "C" void kernel_launch(void* const* d_in, const int* in_sizes, int n_in,
                              void* d_out, int out_size, void* d_ws, size_t ws_size,
                              hipStream_t stream) {
    const float* x     = (const float*)d_in[0];
    const int*   ei    = (const int*)d_in[1];
    const float* w1l   = (const float*)d_in[2];
    const float* b1l   = (const float*)d_in[3];
    const float* w1r   = (const float*)d_in[4];
    const float* gamma = (const float*)d_in[5];
    const float* beta  = (const float*)d_in[6];
    const float* w2l   = (const float*)d_in[7];
    const float* b2l   = (const float*)d_in[8];
    const float* w2r   = (const float*)d_in[9];
    const float* wfc   = (const float*)d_in[10];
    const float* bfc   = (const float*)d_in[11];
    float* out = (float*)d_out;

    float* W = (float*)d_ws;
    int* deg8  = (int*)(W + OFS_DEG8);
    int* deg   = (int*)(W + OFS_DEG);
    int* rp    = (int*)(W + OFS_RP);
    int* bsum  = (int*)(W + OFS_BSUM);
    unsigned short* rank = (unsigned short*)(W + OFS_RANK);
    int* csr   = (int*)(W + OFS_CSR);
    float* inv   = W + OFS_INV;
    float* has   = W + OFS_HAS;
    unsigned* xb   = (unsigned*)(W + OFS_XB);
    unsigned* xb8  = (unsigned*)(W + OFS_XB8);
    unsigned* a1b  = (unsigned*)(W + OFS_A1B);
    unsigned* h1b  = (unsigned*)(W + OFS_H1B);
    unsigned* h1f8 = (unsigned*)(W + OFS_H1F8);
    unsigned* a2b  = (unsigned*)(W + OFS_A2B);
    unsigned short* W1T  = (unsigned short*)(W + OFS_W1T);
    unsigned short* W2T  = (unsigned short*)(W + OFS_W2T);
    unsigned short* wfcT = (unsigned short*)(W + OFS_WFCT);
    float* stats = W + OFS_STATS;          // [sc|sh|sc'|sh'] (512)
    float* part  = W + OFS_PART;

    hipMemsetAsync(deg8, 0, 8 * NN * sizeof(int), stream);

    k_init<<<CAST_BLOCKS + PREP_BLOCKS, 256, 0, stream>>>(
        (const float4*)x, (uint2*)xb, xb8, w1l, w1r, w2l, w2r, wfc, W1T, W2T, wfcT);
    k_rank <<<NE / 256, 256, 0, stream>>>(ei, deg8, rank);
    k_scan1<<<NB1, 256, 0, stream>>>(deg8, deg, bsum);
    k_scan3<<<NB1, 256, 0, stream>>>(deg, bsum, rp, deg8, inv, has);
    k_fill <<<NE / 256, 256, 0, stream>>>(ei, rank, deg8, csr);

    k_agg1 <<<NN / 32, 256, 0, stream>>>((const uint2*)xb8, csr, rp, deg, inv, (uint4*)a1b);
    k_gemm1<<<PART_BLOCKS, 256, 0, stream>>>((const uint4*)a1b, (const uint4*)xb,
                                             (const uint4*)W1T, b1l, (uint4*)h1b,
                                             (uint2*)h1f8, part);
    k_bnfin<<<1, 128, 0, stream>>>(part, gamma, beta, stats);
    k_agg2 <<<NN / 32, 256, 0, stream>>>((const uint4*)h1f8, csr, rp, deg, inv, has,
                                         stats + 256, (uint4*)a2b);
    k_gemm2<<<NT1, 256, 0, stream>>>((const uint4*)a2b, (const uint4*)h1b, stats,
                                     (const uint4*)W2T, b2l, (const uint4*)wfcT, bfc, out);
}